// Round 5
// baseline (3217.872 us; speedup 1.0000x reference)
//
#include <hip/hip_runtime.h>
#include <stdint.h>

// Problem constants
constexpr int N  = 20000;    // nodes
constexpr int E  = 320000;   // edges
constexpr int H  = 256;      // hidden
constexpr int FEAT = 64;     // FE == FV
constexpr int NL = 4;        // layers
constexpr int FL = 1024;
constexpr int NB_E = E / 32; // edge blocks per pass

typedef unsigned short u16;
typedef short bf16x8 __attribute__((ext_vector_type(8)));
typedef float f32x4 __attribute__((ext_vector_type(4)));

// ---------------- bf16 helpers (manual, RNE) ----------------
__device__ __forceinline__ float bf2f(u16 u) {
    union { uint32_t i; float f; } v; v.i = ((uint32_t)u) << 16; return v.f;
}
__device__ __forceinline__ u16 f2bf(float f) {
    union { uint32_t i; float f; } v; v.f = f;
    uint32_t r = v.i + 0x7FFFu + ((v.i >> 16) & 1u);
    return (u16)(r >> 16);
}
__device__ __forceinline__ float sigmf(float x) { return 1.f / (1.f + __expf(-x)); }
__device__ __forceinline__ float tanhf_(float x) { return 2.f / (1.f + __expf(-2.f * x)) - 1.f; }

// order-preserving float<->u32 encoding (for atomic max over signed floats)
__device__ __forceinline__ unsigned int encf(float x) {
    unsigned int u = __float_as_uint(x);
    return (u & 0x80000000u) ? ~u : (u | 0x80000000u);
}
__device__ __forceinline__ float decf(unsigned int k) {
    unsigned int u = (k & 0x80000000u) ? (k ^ 0x80000000u) : ~k;
    return __uint_as_float(u);
}

// B-fragment load: bf16 direct, or fp32 + inline convert (fallback when ws too small)
template <bool W16>
__device__ __forceinline__ bf16x8 ldb(const u16* wb, const float* wf, size_t off) {
    if constexpr (W16) {
        return *(const bf16x8*)(wb + off);
    } else {
        float4 b0 = *(const float4*)(wf + off);
        float4 b1 = *(const float4*)(wf + off + 4);
        bf16x8 r;
        r[0] = (short)f2bf(b0.x); r[1] = (short)f2bf(b0.y);
        r[2] = (short)f2bf(b0.z); r[3] = (short)f2bf(b0.w);
        r[4] = (short)f2bf(b1.x); r[5] = (short)f2bf(b1.y);
        r[6] = (short)f2bf(b1.z); r[7] = (short)f2bf(b1.w);
        return r;
    }
}

// ---------------- K0: fuse fin+out linear layers ----------------
__global__ void k_fuse_final(const float* __restrict__ fin_w, const float* __restrict__ fin_b,
                             const float* __restrict__ out_w, const float* __restrict__ out_b,
                             float* __restrict__ w_fo) {
    int h = threadIdx.x;
    float acc = 0.f;
    for (int f = 0; f < FL; ++f) acc = fmaf(out_w[f], fin_w[(size_t)f * H + h], acc);
    w_fo[h] = acc;
    if (h == 0) {
        float b = 0.f;
        for (int f = 0; f < FL; ++f) b = fmaf(out_w[f], fin_b[f], b);
        w_fo[H] = b + out_b[0];
    }
}

// ---------------- weight convert fp32 -> bf16 ----------------
__global__ void k_cvt_w(const float* __restrict__ w, u16* __restrict__ o, int n4) {
    int i = blockIdx.x * 256 + threadIdx.x;
    if (i < n4) {
        float4 v = *(const float4*)(w + (size_t)i * 4);
        *(ushort4*)(o + (size_t)i * 4) = make_ushort4(f2bf(v.x), f2bf(v.y), f2bf(v.z), f2bf(v.w));
    }
}

// ---------------- CSR build (dual; entries carry {e, src, dst, node}) ----------------
__global__ void k_zero_int(int* __restrict__ p, int n) {
    int i = blockIdx.x * 256 + threadIdx.x;
    if (i < n) p[i] = 0;
}
__global__ void k_zero_f64(double* __restrict__ p, int n) {
    int i = blockIdx.x * 256 + threadIdx.x;
    if (i < n) p[i] = 0.0;
}
__global__ void k_hist2(const int* __restrict__ src, const int* __restrict__ dst,
                        int* __restrict__ curS, int* __restrict__ curD) {
    int e = blockIdx.x * 256 + threadIdx.x;
    if (e < E) { atomicAdd(&curS[src[e]], 1); atomicAdd(&curD[dst[e]], 1); }
}
__global__ void k_scan(int* __restrict__ cur) {
    __shared__ int cs[256];
    int t = threadIdx.x;
    constexpr int CH = (N + 255) / 256;
    int beg = t * CH, end = min(beg + CH, N);
    int s = 0;
    for (int i = beg; i < end; ++i) s += cur[i];
    cs[t] = s;
    __syncthreads();
    for (int off = 1; off < 256; off <<= 1) {
        int v = cs[t];
        int u = (t >= off) ? cs[t - off] : 0;
        __syncthreads();
        cs[t] = v + u;
        __syncthreads();
    }
    int run = (t > 0) ? cs[t - 1] : 0;
    for (int i = beg; i < end; ++i) { int d = cur[i]; cur[i] = run; run += d; }
}
// fill both CSRs; each entry records edge id, both endpoints, and the owning node
__global__ void k_fill_pair(const int* __restrict__ src, const int* __restrict__ dst,
                            int* __restrict__ curS, int* __restrict__ curD,
                            int4* __restrict__ adjS, int4* __restrict__ adjD) {
    int e = blockIdx.x * 256 + threadIdx.x;
    if (e < E) {
        int s = src[e], d = dst[e];
        int p = atomicAdd(&curS[s], 1); adjS[p] = make_int4(e, s, d, s);
        int q = atomicAdd(&curD[d], 1); adjD[q] = make_int4(e, s, d, d);
    }
    // after this kernel, curS[v]/curD[v] hold END offsets of node v
}
__global__ void k_fill_u32(unsigned int* __restrict__ p, unsigned int val) {
    size_t i = ((size_t)blockIdx.x * 256 + threadIdx.x) * 4;
    uint4 v = make_uint4(val, val, val, val);
    *(uint4*)(p + i) = v;
}

// ---------------- MFMA input projection: C[M,256] = A[M,64] @ W[256,64]^T + b, bf16 out ----------------
template <bool W16>
__global__ __launch_bounds__(256, 3) void k_proj_mfma(
    const float* __restrict__ A, const u16* __restrict__ wb, const float* __restrict__ wf,
    const float* __restrict__ bias, u16* __restrict__ C, int M)
{
    __shared__ u16 As[64][72];
    int t = threadIdx.x;
    int row0 = blockIdx.x * 64;
    int r = t >> 2, q = t & 3;
    if (row0 + r < M) {
        const float* gp = A + (size_t)(row0 + r) * FEAT + q * 16;
#pragma unroll
        for (int i = 0; i < 4; ++i) {
            float4 v = *(const float4*)(gp + i * 4);
            *(ushort4*)&As[r][q * 16 + i * 4] = make_ushort4(f2bf(v.x), f2bf(v.y), f2bf(v.z), f2bf(v.w));
        }
    } else {
#pragma unroll
        for (int i = 0; i < 4; ++i) *(ushort4*)&As[r][q * 16 + i * 4] = make_ushort4(0, 0, 0, 0);
    }
    __syncthreads();
    int w = t >> 6, l = t & 63, lane16 = l & 15, quad = l >> 4;
    f32x4 acc[4][4];
#pragma unroll
    for (int i = 0; i < 4; ++i)
#pragma unroll
        for (int j = 0; j < 4; ++j) acc[i][j] = (f32x4){0.f, 0.f, 0.f, 0.f};
#pragma unroll
    for (int k0 = 0; k0 < FEAT; k0 += 32) {
        bf16x8 a[4], b[4];
#pragma unroll
        for (int mt = 0; mt < 4; ++mt)
            a[mt] = *(const bf16x8*)&As[mt * 16 + lane16][k0 + quad * 8];
#pragma unroll
        for (int nt = 0; nt < 4; ++nt)
            b[nt] = ldb<W16>(wb, wf, (size_t)(w * 16 + nt * 64 + lane16) * FEAT + k0 + quad * 8);
#pragma unroll
        for (int mt = 0; mt < 4; ++mt)
#pragma unroll
            for (int nt = 0; nt < 4; ++nt)
                acc[mt][nt] = __builtin_amdgcn_mfma_f32_16x16x32_bf16(a[mt], b[nt], acc[mt][nt], 0, 0, 0);
    }
#pragma unroll
    for (int nt = 0; nt < 4; ++nt) {
        int col = w * 16 + nt * 64 + lane16;
        float bv = bias[col];
#pragma unroll
        for (int mt = 0; mt < 4; ++mt)
#pragma unroll
            for (int reg = 0; reg < 4; ++reg) {
                int row = mt * 16 + quad * 4 + reg;
                if (row0 + row < M)
                    C[(size_t)(row0 + row) * H + col] = f2bf(acc[mt][nt][reg] + bv);
            }
    }
}

// ---------------- MFMA node GEMM: vp = v_in @ Lv_w^T (Lv_b cancels in BN) ----------------
template <bool W16>
__global__ __launch_bounds__(256, 2) void k_node_mfma(
    const u16* __restrict__ A, const u16* __restrict__ wb, const float* __restrict__ wf,
    u16* __restrict__ C)
{
    __shared__ u16 As[64][264];
    int t = threadIdx.x;
    int row0 = blockIdx.x * 64;
    int rows = min(64, N - row0);
    int r = t >> 2, q = t & 3;
    if (r < rows) {
        const u16* gp = A + (size_t)(row0 + r) * H + q * 64;
#pragma unroll
        for (int i = 0; i < 16; ++i)
            *(ushort4*)&As[r][q * 64 + i * 4] = *(const ushort4*)(gp + i * 4);
    } else {
#pragma unroll
        for (int i = 0; i < 16; ++i) *(ushort4*)&As[r][q * 64 + i * 4] = make_ushort4(0, 0, 0, 0);
    }
    __syncthreads();
    int w = t >> 6, l = t & 63, lane16 = l & 15, quad = l >> 4;
    f32x4 acc[4][4];
#pragma unroll
    for (int i = 0; i < 4; ++i)
#pragma unroll
        for (int j = 0; j < 4; ++j) acc[i][j] = (f32x4){0.f, 0.f, 0.f, 0.f};
    for (int k0 = 0; k0 < H; k0 += 32) {
        bf16x8 a[4], b[4];
#pragma unroll
        for (int mt = 0; mt < 4; ++mt)
            a[mt] = *(const bf16x8*)&As[mt * 16 + lane16][k0 + quad * 8];
#pragma unroll
        for (int nt = 0; nt < 4; ++nt)
            b[nt] = ldb<W16>(wb, wf, (size_t)(w * 16 + nt * 64 + lane16) * H + k0 + quad * 8);
#pragma unroll
        for (int mt = 0; mt < 4; ++mt)
#pragma unroll
            for (int nt = 0; nt < 4; ++nt)
                acc[mt][nt] = __builtin_amdgcn_mfma_f32_16x16x32_bf16(a[mt], b[nt], acc[mt][nt], 0, 0, 0);
    }
#pragma unroll
    for (int nt = 0; nt < 4; ++nt) {
        int col = w * 16 + nt * 64 + lane16;
#pragma unroll
        for (int mt = 0; mt < 4; ++mt)
#pragma unroll
            for (int reg = 0; reg < 4; ++reg) {
                int row = mt * 16 + quad * 4 + reg;
                if (row < rows)
                    C[(size_t)(row0 + row) * H + col] = f2bf(acc[mt][nt][reg]);
            }
    }
}

// ---------------- MFMA edge pass v7: v6 + plain-store BN partials (no stats atomics) ----------------
// raw[e][n] = (e_in @ Le_w^T)[e][n] + vp[src_e][n] + vp[dst_e][n]
// FIRST (dst CSR): BN stats + raw segmented max (interior runs -> plain stores).
//   PART: stats written as per-block f32 partials (plain coalesced stores), reduced by
//   k_stats_reduce. !PART: legacy 64-slice f64 atomics (ws fallback).
// !FIRST (src CSR): raw segmented max (interior runs -> plain load/max/store) +
//   e_in += relu(affine(raw)).
template <bool FIRST, bool PART>
__global__ __launch_bounds__(256, 4) void k_edge_mfma(
    const u16* __restrict__ ein, const u16* __restrict__ wbf,
    const u16* __restrict__ vp, const int4* __restrict__ adj,
    const int* __restrict__ endo,
    unsigned int* __restrict__ vie, double* __restrict__ stats_e,
    float* __restrict__ part,
    const float* __restrict__ scale, const float* __restrict__ shift,
    u16* __restrict__ ein_rw)
{
    __shared__ u16 As[32][264];      // K-loop A tile; aliased as praw afterwards
    __shared__ u16 Us[32][264];      // vp[src]+vp[dst]
    __shared__ int s_edge[32];
    __shared__ int s_node[32];
    __shared__ int s_int[32];        // interior flag per row
    u16 (*praw)[264] = As;

    int t = threadIdx.x;
    int p0 = blockIdx.x * 32;
    if (t < 32) {
        int4 en = adj[p0 + t];
        s_edge[t] = en.x; s_node[t] = en.w;
        int nd = en.w;
        int st = (nd == 0) ? 0 : endo[nd - 1];
        int ee = endo[nd];
        s_int[t] = (st >= p0) && (ee <= p0 + 32);
    }
    __syncthreads();
    int r = t >> 3, q = t & 7;       // r: row 0..31, q: 32-col chunk 0..7
    {
        int4 en = adj[p0 + r];
        const u16* gp = ein + (size_t)en.x * H + q * 32;
        const u16* vs = vp + (size_t)en.y * H + q * 32;
        const u16* vd = vp + (size_t)en.z * H + q * 32;
#pragma unroll
        for (int i = 0; i < 8; ++i)
            *(ushort4*)&As[r][q * 32 + i * 4] = *(const ushort4*)(gp + i * 4);
#pragma unroll
        for (int i = 0; i < 8; ++i) {
            ushort4 a4 = *(const ushort4*)(vs + i * 4);
            ushort4 b4 = *(const ushort4*)(vd + i * 4);
            *(ushort4*)&Us[r][q * 32 + i * 4] = make_ushort4(
                f2bf(bf2f(a4.x) + bf2f(b4.x)), f2bf(bf2f(a4.y) + bf2f(b4.y)),
                f2bf(bf2f(a4.z) + bf2f(b4.z)), f2bf(bf2f(a4.w) + bf2f(b4.w)));
        }
    }
    __syncthreads();

    int w = t >> 6, l = t & 63, lane16 = l & 15, quad = l >> 4;
    f32x4 acc[2][4];
#pragma unroll
    for (int i = 0; i < 2; ++i)
#pragma unroll
        for (int j = 0; j < 4; ++j) acc[i][j] = (f32x4){0.f, 0.f, 0.f, 0.f};
    const u16* wb0 = wbf + (size_t)(w * 64 + lane16) * H + quad * 8;
    for (int k0 = 0; k0 < H; k0 += 32) {
        bf16x8 a[2], b[4];
#pragma unroll
        for (int mt = 0; mt < 2; ++mt)
            a[mt] = *(const bf16x8*)&As[mt * 16 + lane16][k0 + quad * 8];
#pragma unroll
        for (int nt = 0; nt < 4; ++nt)
            b[nt] = *(const bf16x8*)(wb0 + (size_t)nt * 16 * H + k0);
#pragma unroll
        for (int mt = 0; mt < 2; ++mt)
#pragma unroll
            for (int nt = 0; nt < 4; ++nt)
                acc[mt][nt] = __builtin_amdgcn_mfma_f32_16x16x32_bf16(a[mt], b[nt], acc[mt][nt], 0, 0, 0);
    }
    __syncthreads();   // As reads complete -> region becomes praw

#pragma unroll
    for (int nt = 0; nt < 4; ++nt) {
        int col = w * 64 + nt * 16 + lane16;
        float s = 0.f, qq = 0.f;
#pragma unroll
        for (int mt = 0; mt < 2; ++mt)
#pragma unroll
            for (int reg = 0; reg < 4; ++reg) {
                int row = mt * 16 + quad * 4 + reg;
                float v = acc[mt][nt][reg] + bf2f(Us[row][col]);
                praw[row][col] = f2bf(v);
                if (FIRST) { s += v; qq += v * v; }
            }
        if (FIRST) {
            s  += __shfl_xor(s, 16, 64);  s  += __shfl_xor(s, 32, 64);
            qq += __shfl_xor(qq, 16, 64); qq += __shfl_xor(qq, 32, 64);
            if (quad == 0) {
                if (PART) {
                    // plain coalesced per-block partials (no atomics)
                    part[(size_t)blockIdx.x * 512 + col] = s;
                    part[(size_t)blockIdx.x * 512 + 256 + col] = qq;
                } else {
                    int slice = blockIdx.x & 63;
                    atomicAdd(&stats_e[(size_t)slice * 512 + col], (double)s);
                    atomicAdd(&stats_e[(size_t)slice * 512 + 256 + col], (double)qq);
                }
            }
        }
    }
    __syncthreads();
    // segmented max walk over node runs: thread t owns column t
    {
        int cur = s_node[0];
        float m = bf2f(praw[0][t]);
#pragma unroll 4
        for (int rr = 1; rr < 32; ++rr) {
            int nd = s_node[rr];
            float v = bf2f(praw[rr][t]);
            if (nd != cur) {
                unsigned int* vpnt = &vie[(size_t)cur * H + t];
                unsigned int em = encf(m);
                if (s_int[rr - 1]) {
                    if (FIRST) *vpnt = em;                       // sole writer, fresh buffer
                    else { unsigned int o = *vpnt; *vpnt = (o > em) ? o : em; }  // sole writer, merge
                } else atomicMax(vpnt, em);
                cur = nd; m = v;
            } else m = fmaxf(m, v);
        }
        unsigned int* vpnt = &vie[(size_t)cur * H + t];
        unsigned int em = encf(m);
        if (s_int[31]) {
            if (FIRST) *vpnt = em;
            else { unsigned int o = *vpnt; *vpnt = (o > em) ? o : em; }
        } else atomicMax(vpnt, em);
    }
    if (!FIRST) {
        u16* gp = ein_rw + (size_t)s_edge[r] * H + q * 32;
        const float* scp = scale + q * 32;
        const float* shp = shift + q * 32;
#pragma unroll
        for (int i = 0; i < 8; ++i) {
            int c = q * 32 + i * 4;
            ushort2 pa = *(const ushort2*)&praw[r][c];
            ushort2 pb = *(const ushort2*)&praw[r][c + 2];
            float4 sc = *(const float4*)(scp + i * 4);
            float4 sh = *(const float4*)(shp + i * 4);
            ushort4 ev = *(const ushort4*)(gp + i * 4);
            float o0 = bf2f(ev.x) + fmaxf(fmaf(bf2f(pa.x), sc.x, sh.x), 0.f);
            float o1 = bf2f(ev.y) + fmaxf(fmaf(bf2f(pa.y), sc.y, sh.y), 0.f);
            float o2 = bf2f(ev.z) + fmaxf(fmaf(bf2f(pb.x), sc.z, sh.z), 0.f);
            float o3 = bf2f(ev.w) + fmaxf(fmaf(bf2f(pb.y), sc.w, sh.w), 0.f);
            *(ushort4*)(gp + i * 4) = make_ushort4(f2bf(o0), f2bf(o1), f2bf(o2), f2bf(o3));
        }
    }
}

// ---------------- partial-stats reduce: 64 slices, plain f64 stores ----------------
__global__ void k_stats_reduce(const float* __restrict__ part, double* __restrict__ stats_e) {
    int b = blockIdx.x;     // 0..63
    int j = threadIdx.x;    // 0..255
    double m = 0.0, q = 0.0;
    for (int s = b; s < NB_E; s += 64) {
        m += (double)part[(size_t)s * 512 + j];
        q += (double)part[(size_t)s * 512 + 256 + j];
    }
    stats_e[(size_t)b * 512 + j] = m;
    stats_e[(size_t)b * 512 + 256 + j] = q;
}

// ---------------- BN finalize (edge: 64-slice reduce) ----------------
__global__ void k_bn_final_e(const double* __restrict__ stats_e,
                             const float* __restrict__ g, const float* __restrict__ b,
                             float* __restrict__ scale, float* __restrict__ shift) {
    int j = threadIdx.x;
    double m = 0.0, q = 0.0;
    for (int s = 0; s < 64; ++s) {
        m += stats_e[(size_t)s * 512 + j];
        q += stats_e[(size_t)s * 512 + 256 + j];
    }
    m /= (double)E;
    double var = q / (double)E - m * m;
    if (var < 0.0) var = 0.0;
    float inv = rsqrtf((float)var + 1e-5f);
    float sc = g[j] * inv;
    scale[j] = sc;
    shift[j] = b[j] - (float)m * sc;
}

// ---------------- BN finalize (node, single slice) ----------------
__global__ void k_bn_final(const double* __restrict__ stats, int base,
                           const float* __restrict__ g, const float* __restrict__ b,
                           double cnt, float* __restrict__ scale, float* __restrict__ shift) {
    int j = threadIdx.x;
    double m = stats[base + j] / cnt;
    double var = stats[base + 256 + j] / cnt - m * m;
    if (var < 0.0) var = 0.0;
    float inv = rsqrtf((float)var + 1e-5f);
    float sc = g[j] * inv;
    scale[j] = sc;
    shift[j] = b[j] - (float)m * sc;
}

// ---------------- vie finalize: decode raw max, affine+relu; untouched (isolated) -> 0 ----------------
__global__ void k_vie_final(unsigned int* __restrict__ vie_u,
                            const float* __restrict__ scale, const float* __restrict__ shift) {
    size_t idx = ((size_t)blockIdx.x * 256 + threadIdx.x) * 4;
    int col = (int)(idx & (size_t)(H - 1));
    uint4 u = *(const uint4*)(vie_u + idx);
    float4 sc = *(const float4*)(scale + col);
    float4 sh = *(const float4*)(shift + col);
    float4 o;
    o.x = (u.x == 0u) ? 0.f : fmaxf(fmaf(decf(u.x), sc.x, sh.x), 0.f);
    o.y = (u.y == 0u) ? 0.f : fmaxf(fmaf(decf(u.y), sc.y, sh.y), 0.f);
    o.z = (u.z == 0u) ? 0.f : fmaxf(fmaf(decf(u.z), sc.z, sh.z), 0.f);
    o.w = (u.w == 0u) ? 0.f : fmaxf(fmaf(decf(u.w), sc.w, sh.w), 0.f);
    *(float4*)((float*)vie_u + idx) = o;
}

// ---------------- MFMA fused GRU: h = (1-z)*n + z*v_in, plus BN stats ----------------
template <bool W16>
__global__ __launch_bounds__(256, 2) void k_gru_mfma(
    const float* __restrict__ vie, const u16* __restrict__ vin,
    const u16* __restrict__ wihb, const float* __restrict__ wihf,
    const u16* __restrict__ whhb, const float* __restrict__ whhf,
    const float* __restrict__ bih, const float* __restrict__ bhh,
    u16* __restrict__ hout, double* __restrict__ stats_v)
{
    __shared__ u16 Ae[64][264];   // vie (bf16-staged)
    __shared__ u16 Av[64][264];   // vin
    __shared__ float csum[256], csq[256];
    int t = threadIdx.x;
    int row0 = blockIdx.x * 64;
    int rows = min(64, N - row0);
    int r = t >> 2, q = t & 3;
    if (r < rows) {
        const float* gp = vie + (size_t)(row0 + r) * H + q * 64;
        const u16* hp = vin + (size_t)(row0 + r) * H + q * 64;
#pragma unroll
        for (int i = 0; i < 16; ++i) {
            float4 v = *(const float4*)(gp + i * 4);
            *(ushort4*)&Ae[r][q * 64 + i * 4] = make_ushort4(f2bf(v.x), f2bf(v.y), f2bf(v.z), f2bf(v.w));
            *(ushort4*)&Av[r][q * 64 + i * 4] = *(const ushort4*)(hp + i * 4);
        }
    } else {
#pragma unroll
        for (int i = 0; i < 16; ++i) {
            *(ushort4*)&Ae[r][q * 64 + i * 4] = make_ushort4(0, 0, 0, 0);
            *(ushort4*)&Av[r][q * 64 + i * 4] = make_ushort4(0, 0, 0, 0);
        }
    }
    __syncthreads();
    int w = t >> 6, l = t & 63, lane16 = l & 15, quad = l >> 4;

    for (int g = 0; g < 4; ++g) {
        int j = g * 64 + w * 16 + lane16;
        f32x4 aR[4], aZ[4], aIG[4], aHG[4];
#pragma unroll
        for (int mt = 0; mt < 4; ++mt) {
            aR[mt] = (f32x4){0.f, 0.f, 0.f, 0.f};  aZ[mt] = (f32x4){0.f, 0.f, 0.f, 0.f};
            aIG[mt] = (f32x4){0.f, 0.f, 0.f, 0.f}; aHG[mt] = (f32x4){0.f, 0.f, 0.f, 0.f};
        }
        for (int k0 = 0; k0 < H; k0 += 32) {
            size_t kq = (size_t)k0 + quad * 8;
            bf16x8 ae[4], av[4];
#pragma unroll
            for (int mt = 0; mt < 4; ++mt) {
                ae[mt] = *(const bf16x8*)&Ae[mt * 16 + lane16][k0 + quad * 8];
                av[mt] = *(const bf16x8*)&Av[mt * 16 + lane16][k0 + quad * 8];
            }
            bf16x8 bri = ldb<W16>(wihb, wihf, (size_t)j * H + kq);
            bf16x8 bzi = ldb<W16>(wihb, wihf, (size_t)(H + j) * H + kq);
            bf16x8 bgi = ldb<W16>(wihb, wihf, (size_t)(2 * H + j) * H + kq);
            bf16x8 brh = ldb<W16>(whhb, whhf, (size_t)j * H + kq);
            bf16x8 bzh = ldb<W16>(whhb, whhf, (size_t)(H + j) * H + kq);
            bf16x8 bgh = ldb<W16>(whhb, whhf, (size_t)(2 * H + j) * H + kq);
#pragma unroll
            for (int mt = 0; mt < 4; ++mt) {
                aR[mt]  = __builtin_amdgcn_mfma_f32_16x16x32_bf16(ae[mt], bri, aR[mt], 0, 0, 0);
                aR[mt]  = __builtin_amdgcn_mfma_f32_16x16x32_bf16(av[mt], brh, aR[mt], 0, 0, 0);
                aZ[mt]  = __builtin_amdgcn_mfma_f32_16x16x32_bf16(ae[mt], bzi, aZ[mt], 0, 0, 0);
                aZ[mt]  = __builtin_amdgcn_mfma_f32_16x16x32_bf16(av[mt], bzh, aZ[mt], 0, 0, 0);
                aIG[mt] = __builtin_amdgcn_mfma_f32_16x16x32_bf16(ae[mt], bgi, aIG[mt], 0, 0, 0);
                aHG[mt] = __builtin_amdgcn_mfma_f32_16x16x32_bf16(av[mt], bgh, aHG[mt], 0, 0, 0);
            }
        }
        float br_ = bih[j] + bhh[j];
        float bz_ = bih[H + j] + bhh[H + j];
        float bgi_ = bih[2 * H + j];
        float bgh_ = bhh[2 * H + j];
        float s = 0.f, qq = 0.f;
#pragma unroll
        for (int mt = 0; mt < 4; ++mt)
#pragma unroll
            for (int reg = 0; reg < 4; ++reg) {
                int row = mt * 16 + quad * 4 + reg;
                float rr = sigmf(aR[mt][reg] + br_);
                float zz = sigmf(aZ[mt][reg] + bz_);
                float nn = tanhf_(aIG[mt][reg] + bgi_ + rr * (aHG[mt][reg] + bgh_));
                float vv = bf2f(Av[row][j]);
                float hv = (1.f - zz) * nn + zz * vv;
                if (row < rows) {
                    hout[(size_t)(row0 + row) * H + j] = f2bf(hv);
                    s += hv; qq += hv * hv;
                }
            }
        s  += __shfl_xor(s, 16, 64);  s  += __shfl_xor(s, 32, 64);
        qq += __shfl_xor(qq, 16, 64); qq += __shfl_xor(qq, 32, 64);
        if (quad == 0) { csum[j] = s; csq[j] = qq; }
    }
    __syncthreads();
    atomicAdd(&stats_v[t], (double)csum[t]);
    atomicAdd(&stats_v[256 + t], (double)csq[t]);
}

// ---------------- vertex update: v_in += relu(h*scale+shift) (bf16 rmw) ----------------
__global__ void k_vertex_update(u16* __restrict__ vin, const u16* __restrict__ h,
                                const float* __restrict__ scale, const float* __restrict__ shift) {
    size_t idx = ((size_t)blockIdx.x * 256 + threadIdx.x) * 4;
    int col = (int)(idx & (size_t)(H - 1));
    ushort4 hv = *(const ushort4*)(h + idx);
    float4 sc = *(const float4*)(scale + col);
    float4 sh = *(const float4*)(shift + col);
    ushort4 vv = *(const ushort4*)(vin + idx);
    float o0 = bf2f(vv.x) + fmaxf(fmaf(bf2f(hv.x), sc.x, sh.x), 0.f);
    float o1 = bf2f(vv.y) + fmaxf(fmaf(bf2f(hv.y), sc.y, sh.y), 0.f);
    float o2 = bf2f(vv.z) + fmaxf(fmaf(bf2f(hv.z), sc.z, sh.z), 0.f);
    float o3 = bf2f(vv.w) + fmaxf(fmaf(bf2f(hv.w), sc.w, sh.w), 0.f);
    *(ushort4*)(vin + idx) = make_ushort4(f2bf(o0), f2bf(o1), f2bf(o2), f2bf(o3));
}

// ---------------- final: out[e] = e_in[e] . w_fo + b_fo ----------------
__global__ __launch_bounds__(256) void k_final(const u16* __restrict__ ein,
                                               const float* __restrict__ w_fo, float* __restrict__ out) {
    int t = threadIdx.x;
    int lane = t & 63;
    int w = (blockIdx.x << 2) + (t >> 6);
    float4 wv = *(const float4*)(w_fo + lane * 4);
    float bfo = w_fo[H];
    int e0 = w * 64;
    for (int e = e0; e < e0 + 64; ++e) {
        ushort4 u = *(const ushort4*)(ein + (size_t)e * H + lane * 4);
        float p = bf2f(u.x) * wv.x + bf2f(u.y) * wv.y + bf2f(u.z) * wv.z + bf2f(u.w) * wv.w;
        for (int off = 32; off > 0; off >>= 1) p += __shfl_down(p, off, 64);
        if (lane == 0) out[e] = p + bfo;
    }
}

// ---------------- pipeline ----------------
template <bool W16, bool PART>
static void run_all(void* const* d_in, void* d_out, void* d_ws, hipStream_t stream) {
    const float* x         = (const float*)d_in[0];
    const float* edge_attr = (const float*)d_in[1];
    const int*   ei        = (const int*)d_in[2];
    const int*   src = ei;
    const int*   dst = ei + E;
    const float* ew  = (const float*)d_in[3];
    const float* eb  = (const float*)d_in[4];
    const float* vw  = (const float*)d_in[5];
    const float* vb  = (const float*)d_in[6];
    const float* Le_w = (const float*)d_in[7];
    // d_in[8] = Le_b : cancels in BN
    const float* Lv_w = (const float*)d_in[9];
    // d_in[10] = Lv_b : cancels in BN
    const float* bne_g = (const float*)d_in[11];
    const float* bne_b = (const float*)d_in[12];
    const float* bnv_g = (const float*)d_in[13];
    const float* bnv_b = (const float*)d_in[14];
    const float* gwih  = (const float*)d_in[15];
    const float* gwhh  = (const float*)d_in[16];
    const float* gbih  = (const float*)d_in[17];
    const float* gbhh  = (const float*)d_in[18];
    const float* fin_w = (const float*)d_in[19];
    const float* fin_b = (const float*)d_in[20];
    const float* out_w = (const float*)d_in[21];
    const float* out_b = (const float*)d_in[22];
    float* out = (float*)d_out;

    const size_t nh = (size_t)N * H, eh = (size_t)E * H;
    char* base = (char*)d_ws;
    size_t off = 0;
    auto alloc = [&](size_t bytes) -> char* {
        char* p = base + off;
        off = (off + bytes + 255) & ~(size_t)255;
        return p;
    };
    float* w_fo = (float*)alloc((H + 1) * sizeof(float));
    u16* v_in = (u16*)alloc(nh * sizeof(u16));
    u16* vp   = (u16*)alloc(nh * sizeof(u16));          // aliased as hbuf after edge passes
    unsigned int* vie_u = (unsigned int*)alloc(nh * sizeof(unsigned int));
    u16* e_in = (u16*)alloc(eh * sizeof(u16));
    u16* wbf  = (u16*)alloc((size_t)NL * H * H * sizeof(u16));   // Le_w bf16 (always)
    double* stats_e = (double*)alloc((size_t)64 * 512 * sizeof(double));
    double* stats_v = (double*)alloc(512 * sizeof(double));
    float* scale_e = (float*)alloc(H * sizeof(float));
    float* shift_e = (float*)alloc(H * sizeof(float));
    float* scale_v = (float*)alloc(H * sizeof(float));
    float* shift_v = (float*)alloc(H * sizeof(float));
    int* curS = (int*)alloc((size_t)N * sizeof(int));
    int* curD = (int*)alloc((size_t)N * sizeof(int));
    int4* adjS = (int4*)alloc((size_t)E * sizeof(int4));
    int4* adjD = (int4*)alloc((size_t)E * sizeof(int4));
    // optional bf16 weight copies (only consumed when W16)
    u16 *wbf_v = nullptr, *wbf_ih = nullptr, *wbf_hh = nullptr, *ew_b = nullptr, *vw_b = nullptr;
    if (W16) {
        wbf_v  = (u16*)alloc((size_t)NL * H * H * sizeof(u16));
        wbf_ih = (u16*)alloc((size_t)NL * 3 * H * H * sizeof(u16));
        wbf_hh = (u16*)alloc((size_t)NL * 3 * H * H * sizeof(u16));
        ew_b   = (u16*)alloc((size_t)H * FEAT * sizeof(u16));
        vw_b   = (u16*)alloc((size_t)H * FEAT * sizeof(u16));
    }
    float* part = nullptr;
    if (PART) part = (float*)alloc((size_t)NB_E * 512 * sizeof(float));
    u16* hbuf = vp;  // vp dead after edge passes; GRU writes here

    // fused final weights; bf16 weight conversions
    k_fuse_final<<<1, 256, 0, stream>>>(fin_w, fin_b, out_w, out_b, w_fo);
    k_cvt_w<<<(NL * H * H / 4 + 255) / 256, 256, 0, stream>>>(Le_w, wbf, NL * H * H / 4);
    if (W16) {
        k_cvt_w<<<(NL * H * H / 4 + 255) / 256, 256, 0, stream>>>(Lv_w, wbf_v, NL * H * H / 4);
        k_cvt_w<<<(NL * 3 * H * H / 4 + 255) / 256, 256, 0, stream>>>(gwih, wbf_ih, NL * 3 * H * H / 4);
        k_cvt_w<<<(NL * 3 * H * H / 4 + 255) / 256, 256, 0, stream>>>(gwhh, wbf_hh, NL * 3 * H * H / 4);
        k_cvt_w<<<(H * FEAT / 4 + 255) / 256, 256, 0, stream>>>(ew, ew_b, H * FEAT / 4);
        k_cvt_w<<<(H * FEAT / 4 + 255) / 256, 256, 0, stream>>>(vw, vw_b, H * FEAT / 4);
    }
    // dual CSR with self-describing entries
    k_zero_int<<<(N + 255) / 256, 256, 0, stream>>>(curS, N);
    k_zero_int<<<(N + 255) / 256, 256, 0, stream>>>(curD, N);
    k_hist2<<<E / 256, 256, 0, stream>>>(src, dst, curS, curD);
    k_scan<<<1, 256, 0, stream>>>(curS);
    k_scan<<<1, 256, 0, stream>>>(curD);
    k_fill_pair<<<E / 256, 256, 0, stream>>>(src, dst, curS, curD, adjS, adjD);
    // input projections (MFMA, bf16 out)
    const int ntile = (N + 63) / 64;
    k_proj_mfma<W16><<<ntile, 256, 0, stream>>>(x, vw_b, vw, vb, v_in, N);
    k_proj_mfma<W16><<<E / 64, 256, 0, stream>>>(edge_attr, ew_b, ew, eb, e_in, E);

    const int nstat = 64 * 512 + 512;
    for (int k = 0; k < NL; ++k) {
        if (PART)
            k_zero_f64<<<2, 256, 0, stream>>>(stats_v, 512);           // only node stats need zero
        else
            k_zero_f64<<<(nstat + 255) / 256, 256, 0, stream>>>(stats_e, nstat);
        k_fill_u32<<<(int)(nh / 4 / 256), 256, 0, stream>>>(vie_u, 0u);
        k_node_mfma<W16><<<ntile, 256, 0, stream>>>(v_in,
            W16 ? wbf_v + (size_t)k * H * H : nullptr, Lv_w + (size_t)k * H * H, vp);
        // dst pass: stats + raw max (interior runs -> plain stores)
        k_edge_mfma<true, PART><<<NB_E, 256, 0, stream>>>(e_in, wbf + (size_t)k * H * H, vp,
                                                          adjD, curD, vie_u, stats_e, part,
                                                          nullptr, nullptr, nullptr);
        if (PART) k_stats_reduce<<<64, 256, 0, stream>>>(part, stats_e);
        k_bn_final_e<<<1, 256, 0, stream>>>(stats_e, bne_g + k * H, bne_b + k * H, scale_e, shift_e);
        // src pass: raw max (interior -> plain merge) + residual into e_in
        k_edge_mfma<false, false><<<NB_E, 256, 0, stream>>>(e_in, wbf + (size_t)k * H * H, vp,
                                                            adjS, curS, vie_u, nullptr, nullptr,
                                                            scale_e, shift_e, e_in);
        k_vie_final<<<(int)(nh / 4 / 256), 256, 0, stream>>>(vie_u, scale_e, shift_e);
        k_gru_mfma<W16><<<ntile, 256, 0, stream>>>((const float*)vie_u, v_in,
            W16 ? wbf_ih + (size_t)k * 3 * H * H : nullptr, gwih + (size_t)k * 3 * H * H,
            W16 ? wbf_hh + (size_t)k * 3 * H * H : nullptr, gwhh + (size_t)k * 3 * H * H,
            gbih + (size_t)k * 3 * H, gbhh + (size_t)k * 3 * H, hbuf, stats_v);
        k_bn_final<<<1, 256, 0, stream>>>(stats_v, 0, bnv_g + k * H, bnv_b + k * H, (double)N, scale_v, shift_v);
        k_vertex_update<<<(int)(nh / 4 / 256), 256, 0, stream>>>(v_in, hbuf, scale_v, shift_v);
    }
    k_final<<<E / 256, 256, 0, stream>>>(e_in, w_fo, out);
}

// ---------------- host entry ----------------
extern "C" void kernel_launch(void* const* d_in, const int* in_sizes, int n_in,
                              void* d_out, int out_size, void* d_ws, size_t ws_size,
                              hipStream_t stream) {
    (void)in_sizes; (void)n_in; (void)out_size;
    const size_t nh = (size_t)N * H, eh = (size_t)E * H;
    auto rup = [](size_t x) { return (x + 255) & ~(size_t)255; };
    size_t need_base = rup((H + 1) * 4) + 2 * rup(nh * 2) + rup(nh * 4) + rup(eh * 2)
                     + rup((size_t)NL * H * H * 2) + rup((size_t)64 * 512 * 8) + rup(512 * 8)
                     + 4 * rup(H * 4) + 2 * rup((size_t)N * 4) + 2 * rup((size_t)E * 16);
    size_t need_w16 = rup((size_t)NL * H * H * 2)
                    + 2 * rup((size_t)NL * 3 * H * H * 2) + 2 * rup((size_t)H * FEAT * 2);
    size_t need_part = rup((size_t)NB_E * 512 * 4);
    bool fit_full = (ws_size == 0) || (ws_size >= need_base + need_w16 + need_part);
    bool fit_w16  = (ws_size >= need_base + need_w16);
    bool fit_part = (ws_size >= need_base + need_part);
    if (fit_full)      run_all<true, true>(d_in, d_out, d_ws, stream);
    else if (fit_w16)  run_all<true, false>(d_in, d_out, d_ws, stream);
    else if (fit_part) run_all<false, true>(d_in, d_out, d_ws, stream);
    else               run_all<false, false>(d_in, d_out, d_ws, stream);
}

// Round 6
// 3030.278 us; speedup vs baseline: 1.0619x; 1.0619x over previous
//
#include <hip/hip_runtime.h>
#include <stdint.h>

// Problem constants
constexpr int N  = 20000;    // nodes
constexpr int E  = 320000;   // edges
constexpr int H  = 256;      // hidden
constexpr int FEAT = 64;     // FE == FV
constexpr int NL = 4;        // layers
constexpr int FL = 1024;
constexpr int NB_E = E / 32; // edge blocks per pass

typedef unsigned short u16;
typedef short bf16x8 __attribute__((ext_vector_type(8)));
typedef float f32x4 __attribute__((ext_vector_type(4)));

// ---------------- bf16 helpers (manual, RNE) ----------------
__device__ __forceinline__ float bf2f(u16 u) {
    union { uint32_t i; float f; } v; v.i = ((uint32_t)u) << 16; return v.f;
}
__device__ __forceinline__ u16 f2bf(float f) {
    union { uint32_t i; float f; } v; v.f = f;
    uint32_t r = v.i + 0x7FFFu + ((v.i >> 16) & 1u);
    return (u16)(r >> 16);
}
__device__ __forceinline__ float sigmf(float x) { return 1.f / (1.f + __expf(-x)); }
__device__ __forceinline__ float tanhf_(float x) { return 2.f / (1.f + __expf(-2.f * x)) - 1.f; }

// order-preserving float<->u32 encoding (for atomic max over signed floats)
__device__ __forceinline__ unsigned int encf(float x) {
    unsigned int u = __float_as_uint(x);
    return (u & 0x80000000u) ? ~u : (u | 0x80000000u);
}
__device__ __forceinline__ float decf(unsigned int k) {
    unsigned int u = (k & 0x80000000u) ? (k ^ 0x80000000u) : ~k;
    return __uint_as_float(u);
}

// B-fragment load: bf16 direct, or fp32 + inline convert (fallback when ws too small)
template <bool W16>
__device__ __forceinline__ bf16x8 ldb(const u16* wb, const float* wf, size_t off) {
    if constexpr (W16) {
        return *(const bf16x8*)(wb + off);
    } else {
        float4 b0 = *(const float4*)(wf + off);
        float4 b1 = *(const float4*)(wf + off + 4);
        bf16x8 r;
        r[0] = (short)f2bf(b0.x); r[1] = (short)f2bf(b0.y);
        r[2] = (short)f2bf(b0.z); r[3] = (short)f2bf(b0.w);
        r[4] = (short)f2bf(b1.x); r[5] = (short)f2bf(b1.y);
        r[6] = (short)f2bf(b1.z); r[7] = (short)f2bf(b1.w);
        return r;
    }
}

// ---------------- K0: fuse fin+out linear layers ----------------
__global__ void k_fuse_final(const float* __restrict__ fin_w, const float* __restrict__ fin_b,
                             const float* __restrict__ out_w, const float* __restrict__ out_b,
                             float* __restrict__ w_fo) {
    int h = threadIdx.x;
    float acc = 0.f;
    for (int f = 0; f < FL; ++f) acc = fmaf(out_w[f], fin_w[(size_t)f * H + h], acc);
    w_fo[h] = acc;
    if (h == 0) {
        float b = 0.f;
        for (int f = 0; f < FL; ++f) b = fmaf(out_w[f], fin_b[f], b);
        w_fo[H] = b + out_b[0];
    }
}

// ---------------- weight convert fp32 -> bf16 ----------------
__global__ void k_cvt_w(const float* __restrict__ w, u16* __restrict__ o, int n4) {
    int i = blockIdx.x * 256 + threadIdx.x;
    if (i < n4) {
        float4 v = *(const float4*)(w + (size_t)i * 4);
        *(ushort4*)(o + (size_t)i * 4) = make_ushort4(f2bf(v.x), f2bf(v.y), f2bf(v.z), f2bf(v.w));
    }
}

// ---------------- CSR build: dst-order edge relabel + src CSR over positions ----------------
__global__ void k_zero_int(int* __restrict__ p, int n) {
    int i = blockIdx.x * 256 + threadIdx.x;
    if (i < n) p[i] = 0;
}
__global__ void k_zero_f64(double* __restrict__ p, int n) {
    int i = blockIdx.x * 256 + threadIdx.x;
    if (i < n) p[i] = 0.0;
}
__global__ void k_hist2(const int* __restrict__ src, const int* __restrict__ dst,
                        int* __restrict__ curS, int* __restrict__ curD) {
    int e = blockIdx.x * 256 + threadIdx.x;
    if (e < E) { atomicAdd(&curS[src[e]], 1); atomicAdd(&curD[dst[e]], 1); }
}
__global__ void k_scan(int* __restrict__ cur) {
    __shared__ int cs[256];
    int t = threadIdx.x;
    constexpr int CH = (N + 255) / 256;
    int beg = t * CH, end = min(beg + CH, N);
    int s = 0;
    for (int i = beg; i < end; ++i) s += cur[i];
    cs[t] = s;
    __syncthreads();
    for (int off = 1; off < 256; off <<= 1) {
        int v = cs[t];
        int u = (t >= off) ? cs[t - off] : 0;
        __syncthreads();
        cs[t] = v + u;
        __syncthreads();
    }
    int run = (t > 0) ? cs[t - 1] : 0;
    for (int i = beg; i < end; ++i) { int d = cur[i]; cur[i] = run; run += d; }
}
// q = position of edge e in dst order. sd2[q]={src,dst,e}; pos[e]=q;
// adjS entries carry {position, src, dst, src-node}.
__global__ void k_fill_perm(const int* __restrict__ src, const int* __restrict__ dst,
                            int* __restrict__ curS, int* __restrict__ curD,
                            int4* __restrict__ adjS, int4* __restrict__ sd2, int* __restrict__ pos) {
    int e = blockIdx.x * 256 + threadIdx.x;
    if (e < E) {
        int s = src[e], d = dst[e];
        int q = atomicAdd(&curD[d], 1);
        sd2[q] = make_int4(s, d, e, 0);
        pos[e] = q;
        int p = atomicAdd(&curS[s], 1);
        adjS[p] = make_int4(q, s, d, s);
    }
    // after this kernel, curS[v]/curD[v] hold END offsets of node v
}
__global__ void k_fill_u32(unsigned int* __restrict__ p, unsigned int val) {
    size_t i = ((size_t)blockIdx.x * 256 + threadIdx.x) * 4;
    uint4 v = make_uint4(val, val, val, val);
    *(uint4*)(p + i) = v;
}

// ---------------- MFMA input projection: C[perm[m],256] = A[m,64] @ W^T + b, bf16 out ----------------
template <bool W16>
__global__ __launch_bounds__(256, 3) void k_proj_mfma(
    const float* __restrict__ A, const u16* __restrict__ wb, const float* __restrict__ wf,
    const float* __restrict__ bias, u16* __restrict__ C, int M, const int* __restrict__ perm)
{
    __shared__ u16 As[64][72];
    int t = threadIdx.x;
    int row0 = blockIdx.x * 64;
    int r = t >> 2, q = t & 3;
    if (row0 + r < M) {
        const float* gp = A + (size_t)(row0 + r) * FEAT + q * 16;
#pragma unroll
        for (int i = 0; i < 4; ++i) {
            float4 v = *(const float4*)(gp + i * 4);
            *(ushort4*)&As[r][q * 16 + i * 4] = make_ushort4(f2bf(v.x), f2bf(v.y), f2bf(v.z), f2bf(v.w));
        }
    } else {
#pragma unroll
        for (int i = 0; i < 4; ++i) *(ushort4*)&As[r][q * 16 + i * 4] = make_ushort4(0, 0, 0, 0);
    }
    __syncthreads();
    int w = t >> 6, l = t & 63, lane16 = l & 15, quad = l >> 4;
    f32x4 acc[4][4];
#pragma unroll
    for (int i = 0; i < 4; ++i)
#pragma unroll
        for (int j = 0; j < 4; ++j) acc[i][j] = (f32x4){0.f, 0.f, 0.f, 0.f};
#pragma unroll
    for (int k0 = 0; k0 < FEAT; k0 += 32) {
        bf16x8 a[4], b[4];
#pragma unroll
        for (int mt = 0; mt < 4; ++mt)
            a[mt] = *(const bf16x8*)&As[mt * 16 + lane16][k0 + quad * 8];
#pragma unroll
        for (int nt = 0; nt < 4; ++nt)
            b[nt] = ldb<W16>(wb, wf, (size_t)(w * 16 + nt * 64 + lane16) * FEAT + k0 + quad * 8);
#pragma unroll
        for (int mt = 0; mt < 4; ++mt)
#pragma unroll
            for (int nt = 0; nt < 4; ++nt)
                acc[mt][nt] = __builtin_amdgcn_mfma_f32_16x16x32_bf16(a[mt], b[nt], acc[mt][nt], 0, 0, 0);
    }
#pragma unroll
    for (int nt = 0; nt < 4; ++nt) {
        int col = w * 16 + nt * 64 + lane16;
        float bv = bias[col];
#pragma unroll
        for (int mt = 0; mt < 4; ++mt)
#pragma unroll
            for (int reg = 0; reg < 4; ++reg) {
                int row = mt * 16 + quad * 4 + reg;
                if (row0 + row < M) {
                    int pr = perm ? perm[row0 + row] : row0 + row;
                    C[(size_t)pr * H + col] = f2bf(acc[mt][nt][reg] + bv);
                }
            }
    }
}

// ---------------- MFMA node GEMM: vp = v_in @ Lv_w^T (Lv_b cancels in BN) ----------------
template <bool W16>
__global__ __launch_bounds__(256, 2) void k_node_mfma(
    const u16* __restrict__ A, const u16* __restrict__ wb, const float* __restrict__ wf,
    u16* __restrict__ C)
{
    __shared__ u16 As[64][264];
    int t = threadIdx.x;
    int row0 = blockIdx.x * 64;
    int rows = min(64, N - row0);
    int r = t >> 2, q = t & 3;
    if (r < rows) {
        const u16* gp = A + (size_t)(row0 + r) * H + q * 64;
#pragma unroll
        for (int i = 0; i < 16; ++i)
            *(ushort4*)&As[r][q * 64 + i * 4] = *(const ushort4*)(gp + i * 4);
    } else {
#pragma unroll
        for (int i = 0; i < 16; ++i) *(ushort4*)&As[r][q * 64 + i * 4] = make_ushort4(0, 0, 0, 0);
    }
    __syncthreads();
    int w = t >> 6, l = t & 63, lane16 = l & 15, quad = l >> 4;
    f32x4 acc[4][4];
#pragma unroll
    for (int i = 0; i < 4; ++i)
#pragma unroll
        for (int j = 0; j < 4; ++j) acc[i][j] = (f32x4){0.f, 0.f, 0.f, 0.f};
    for (int k0 = 0; k0 < H; k0 += 32) {
        bf16x8 a[4], b[4];
#pragma unroll
        for (int mt = 0; mt < 4; ++mt)
            a[mt] = *(const bf16x8*)&As[mt * 16 + lane16][k0 + quad * 8];
#pragma unroll
        for (int nt = 0; nt < 4; ++nt)
            b[nt] = ldb<W16>(wb, wf, (size_t)(w * 16 + nt * 64 + lane16) * H + k0 + quad * 8);
#pragma unroll
        for (int mt = 0; mt < 4; ++mt)
#pragma unroll
            for (int nt = 0; nt < 4; ++nt)
                acc[mt][nt] = __builtin_amdgcn_mfma_f32_16x16x32_bf16(a[mt], b[nt], acc[mt][nt], 0, 0, 0);
    }
#pragma unroll
    for (int nt = 0; nt < 4; ++nt) {
        int col = w * 16 + nt * 64 + lane16;
#pragma unroll
        for (int mt = 0; mt < 4; ++mt)
#pragma unroll
            for (int reg = 0; reg < 4; ++reg) {
                int row = mt * 16 + quad * 4 + reg;
                if (row < rows)
                    C[(size_t)(row0 + row) * H + col] = f2bf(acc[mt][nt][reg]);
            }
    }
}

// ---------------- edge pass A (dst order, STREAMING): stats + raw segmented max ----------------
// e_in2 is stored in dst-CSR order: rows [p0, p0+32) are sequential reads, node runs
// contiguous, vie writes mostly plain stores. Only vp rows are gathered.
__global__ __launch_bounds__(256, 4) void k_edge_first(
    const u16* __restrict__ ein2, const u16* __restrict__ wbf,
    const u16* __restrict__ vp, const int4* __restrict__ sd2,
    const int* __restrict__ endo,
    unsigned int* __restrict__ vie, double* __restrict__ stats_e)
{
    __shared__ u16 As[32][264];      // K-loop A tile; aliased as praw afterwards
    __shared__ u16 Us[32][264];      // vp[src]+vp[dst]
    __shared__ int s_node[32];
    __shared__ int s_int[32];
    u16 (*praw)[264] = As;

    int t = threadIdx.x;
    int p0 = blockIdx.x * 32;
    int r = t >> 3, q = t & 7;       // r: row 0..31, q: 32-col chunk 0..7
    {
        int4 en = sd2[p0 + r];       // {src, dst, e, 0}
        const u16* gp = ein2 + (size_t)(p0 + r) * H + q * 32;   // sequential
        const u16* vs = vp + (size_t)en.x * H + q * 32;
        const u16* vd = vp + (size_t)en.y * H + q * 32;
#pragma unroll
        for (int i = 0; i < 8; ++i)
            *(ushort4*)&As[r][q * 32 + i * 4] = *(const ushort4*)(gp + i * 4);
#pragma unroll
        for (int i = 0; i < 8; ++i) {
            ushort4 a4 = *(const ushort4*)(vs + i * 4);
            ushort4 b4 = *(const ushort4*)(vd + i * 4);
            *(ushort4*)&Us[r][q * 32 + i * 4] = make_ushort4(
                f2bf(bf2f(a4.x) + bf2f(b4.x)), f2bf(bf2f(a4.y) + bf2f(b4.y)),
                f2bf(bf2f(a4.z) + bf2f(b4.z)), f2bf(bf2f(a4.w) + bf2f(b4.w)));
        }
    }
    if (t < 32) {
        int nd = sd2[p0 + t].y;
        s_node[t] = nd;
        int st = (nd == 0) ? 0 : endo[nd - 1];
        int ee = endo[nd];
        s_int[t] = (st >= p0) && (ee <= p0 + 32);
    }
    __syncthreads();

    int w = t >> 6, l = t & 63, lane16 = l & 15, quad = l >> 4;
    f32x4 acc[2][4];
#pragma unroll
    for (int i = 0; i < 2; ++i)
#pragma unroll
        for (int j = 0; j < 4; ++j) acc[i][j] = (f32x4){0.f, 0.f, 0.f, 0.f};
    const u16* wb0 = wbf + (size_t)(w * 64 + lane16) * H + quad * 8;
    for (int k0 = 0; k0 < H; k0 += 32) {
        bf16x8 a[2], b[4];
#pragma unroll
        for (int mt = 0; mt < 2; ++mt)
            a[mt] = *(const bf16x8*)&As[mt * 16 + lane16][k0 + quad * 8];
#pragma unroll
        for (int nt = 0; nt < 4; ++nt)
            b[nt] = *(const bf16x8*)(wb0 + (size_t)nt * 16 * H + k0);
#pragma unroll
        for (int mt = 0; mt < 2; ++mt)
#pragma unroll
            for (int nt = 0; nt < 4; ++nt)
                acc[mt][nt] = __builtin_amdgcn_mfma_f32_16x16x32_bf16(a[mt], b[nt], acc[mt][nt], 0, 0, 0);
    }
    __syncthreads();   // As reads complete -> region becomes praw

#pragma unroll
    for (int nt = 0; nt < 4; ++nt) {
        int col = w * 64 + nt * 16 + lane16;
        float s = 0.f, qq = 0.f;
#pragma unroll
        for (int mt = 0; mt < 2; ++mt)
#pragma unroll
            for (int reg = 0; reg < 4; ++reg) {
                int row = mt * 16 + quad * 4 + reg;
                float v = acc[mt][nt][reg] + bf2f(Us[row][col]);
                praw[row][col] = f2bf(v);
                s += v; qq += v * v;
            }
        s  += __shfl_xor(s, 16, 64);  s  += __shfl_xor(s, 32, 64);
        qq += __shfl_xor(qq, 16, 64); qq += __shfl_xor(qq, 32, 64);
        if (quad == 0) {
            int slice = blockIdx.x & 63;
            atomicAdd(&stats_e[(size_t)slice * 512 + col], (double)s);
            atomicAdd(&stats_e[(size_t)slice * 512 + 256 + col], (double)qq);
        }
    }
    __syncthreads();
    // segmented max walk (nodes contiguous): thread t owns column t
    {
        int cur = s_node[0];
        float m = bf2f(praw[0][t]);
        for (int rr = 1; rr < 32; ++rr) {
            int nd = s_node[rr];
            float v = bf2f(praw[rr][t]);
            if (nd != cur) {
                if (s_int[rr - 1]) vie[(size_t)cur * H + t] = encf(m);   // sole writer
                else atomicMax(&vie[(size_t)cur * H + t], encf(m));
                cur = nd; m = v;
            } else m = fmaxf(m, v);
        }
        if (s_int[31]) vie[(size_t)cur * H + t] = encf(m);
        else atomicMax(&vie[(size_t)cur * H + t], encf(m));
    }
}

// ---------------- edge pass B (src CSR, gathered): raw max + e_in2 residual update ----------------
__global__ __launch_bounds__(256, 4) void k_edge_second(
    const u16* __restrict__ ein2, const u16* __restrict__ wbf,
    const u16* __restrict__ vp, const int4* __restrict__ adj,
    unsigned int* __restrict__ vie,
    const float* __restrict__ scale, const float* __restrict__ shift,
    u16* __restrict__ ein_rw)
{
    __shared__ u16 As[32][264];      // K-loop A tile; aliased as praw afterwards
    __shared__ u16 Us[32][264];      // vp[src]+vp[dst]
    __shared__ int s_pos[32];
    __shared__ int s_node[32];
    u16 (*praw)[264] = As;

    int t = threadIdx.x;
    int p0 = blockIdx.x * 32;
    int r = t >> 3, q = t & 7;
    {
        int4 en = adj[p0 + r];       // {pos, src, dst, src-node}
        const u16* gp = ein2 + (size_t)en.x * H + q * 32;
        const u16* vs = vp + (size_t)en.y * H + q * 32;
        const u16* vd = vp + (size_t)en.z * H + q * 32;
#pragma unroll
        for (int i = 0; i < 8; ++i)
            *(ushort4*)&As[r][q * 32 + i * 4] = *(const ushort4*)(gp + i * 4);
#pragma unroll
        for (int i = 0; i < 8; ++i) {
            ushort4 a4 = *(const ushort4*)(vs + i * 4);
            ushort4 b4 = *(const ushort4*)(vd + i * 4);
            *(ushort4*)&Us[r][q * 32 + i * 4] = make_ushort4(
                f2bf(bf2f(a4.x) + bf2f(b4.x)), f2bf(bf2f(a4.y) + bf2f(b4.y)),
                f2bf(bf2f(a4.z) + bf2f(b4.z)), f2bf(bf2f(a4.w) + bf2f(b4.w)));
        }
    }
    if (t < 32) {
        int4 en = adj[p0 + t];
        s_pos[t] = en.x; s_node[t] = en.w;
    }
    __syncthreads();

    int w = t >> 6, l = t & 63, lane16 = l & 15, quad = l >> 4;
    f32x4 acc[2][4];
#pragma unroll
    for (int i = 0; i < 2; ++i)
#pragma unroll
        for (int j = 0; j < 4; ++j) acc[i][j] = (f32x4){0.f, 0.f, 0.f, 0.f};
    const u16* wb0 = wbf + (size_t)(w * 64 + lane16) * H + quad * 8;
    for (int k0 = 0; k0 < H; k0 += 32) {
        bf16x8 a[2], b[4];
#pragma unroll
        for (int mt = 0; mt < 2; ++mt)
            a[mt] = *(const bf16x8*)&As[mt * 16 + lane16][k0 + quad * 8];
#pragma unroll
        for (int nt = 0; nt < 4; ++nt)
            b[nt] = *(const bf16x8*)(wb0 + (size_t)nt * 16 * H + k0);
#pragma unroll
        for (int mt = 0; mt < 2; ++mt)
#pragma unroll
            for (int nt = 0; nt < 4; ++nt)
                acc[mt][nt] = __builtin_amdgcn_mfma_f32_16x16x32_bf16(a[mt], b[nt], acc[mt][nt], 0, 0, 0);
    }
    __syncthreads();   // As reads complete -> region becomes praw

#pragma unroll
    for (int nt = 0; nt < 4; ++nt) {
        int col = w * 64 + nt * 16 + lane16;
#pragma unroll
        for (int mt = 0; mt < 2; ++mt)
#pragma unroll
            for (int reg = 0; reg < 4; ++reg) {
                int row = mt * 16 + quad * 4 + reg;
                praw[row][col] = f2bf(acc[mt][nt][reg] + bf2f(Us[row][col]));
            }
    }
    __syncthreads();
    // segmented max walk over node runs: thread t owns column t
    {
        int cur = s_node[0];
        float m = bf2f(praw[0][t]);
        for (int rr = 1; rr < 32; ++rr) {
            int nd = s_node[rr];
            float v = bf2f(praw[rr][t]);
            if (nd != cur) {
                atomicMax(&vie[(size_t)cur * H + t], encf(m));
                cur = nd; m = v;
            } else m = fmaxf(m, v);
        }
        atomicMax(&vie[(size_t)cur * H + t], encf(m));
    }
    {
        u16* gp = ein_rw + (size_t)s_pos[r] * H + q * 32;
        const float* scp = scale + q * 32;
        const float* shp = shift + q * 32;
#pragma unroll
        for (int i = 0; i < 8; ++i) {
            int c = q * 32 + i * 4;
            ushort2 pa = *(const ushort2*)&praw[r][c];
            ushort2 pb = *(const ushort2*)&praw[r][c + 2];
            float4 sc = *(const float4*)(scp + i * 4);
            float4 sh = *(const float4*)(shp + i * 4);
            ushort4 ev = *(const ushort4*)(gp + i * 4);
            float o0 = bf2f(ev.x) + fmaxf(fmaf(bf2f(pa.x), sc.x, sh.x), 0.f);
            float o1 = bf2f(ev.y) + fmaxf(fmaf(bf2f(pa.y), sc.y, sh.y), 0.f);
            float o2 = bf2f(ev.z) + fmaxf(fmaf(bf2f(pb.x), sc.z, sh.z), 0.f);
            float o3 = bf2f(ev.w) + fmaxf(fmaf(bf2f(pb.y), sc.w, sh.w), 0.f);
            *(ushort4*)(gp + i * 4) = make_ushort4(f2bf(o0), f2bf(o1), f2bf(o2), f2bf(o3));
        }
    }
}

// ---------------- BN finalize (edge: 64-slice reduce) ----------------
__global__ void k_bn_final_e(const double* __restrict__ stats_e,
                             const float* __restrict__ g, const float* __restrict__ b,
                             float* __restrict__ scale, float* __restrict__ shift) {
    int j = threadIdx.x;
    double m = 0.0, q = 0.0;
    for (int s = 0; s < 64; ++s) {
        m += stats_e[(size_t)s * 512 + j];
        q += stats_e[(size_t)s * 512 + 256 + j];
    }
    m /= (double)E;
    double var = q / (double)E - m * m;
    if (var < 0.0) var = 0.0;
    float inv = rsqrtf((float)var + 1e-5f);
    float sc = g[j] * inv;
    scale[j] = sc;
    shift[j] = b[j] - (float)m * sc;
}

// ---------------- BN finalize (node, single slice) ----------------
__global__ void k_bn_final(const double* __restrict__ stats, int base,
                           const float* __restrict__ g, const float* __restrict__ b,
                           double cnt, float* __restrict__ scale, float* __restrict__ shift) {
    int j = threadIdx.x;
    double m = stats[base + j] / cnt;
    double var = stats[base + 256 + j] / cnt - m * m;
    if (var < 0.0) var = 0.0;
    float inv = rsqrtf((float)var + 1e-5f);
    float sc = g[j] * inv;
    scale[j] = sc;
    shift[j] = b[j] - (float)m * sc;
}

// ---------------- vie finalize: decode raw max, affine+relu; untouched (isolated) -> 0 ----------------
__global__ void k_vie_final(unsigned int* __restrict__ vie_u,
                            const float* __restrict__ scale, const float* __restrict__ shift) {
    size_t idx = ((size_t)blockIdx.x * 256 + threadIdx.x) * 4;
    int col = (int)(idx & (size_t)(H - 1));
    uint4 u = *(const uint4*)(vie_u + idx);
    float4 sc = *(const float4*)(scale + col);
    float4 sh = *(const float4*)(shift + col);
    float4 o;
    o.x = (u.x == 0u) ? 0.f : fmaxf(fmaf(decf(u.x), sc.x, sh.x), 0.f);
    o.y = (u.y == 0u) ? 0.f : fmaxf(fmaf(decf(u.y), sc.y, sh.y), 0.f);
    o.z = (u.z == 0u) ? 0.f : fmaxf(fmaf(decf(u.z), sc.z, sh.z), 0.f);
    o.w = (u.w == 0u) ? 0.f : fmaxf(fmaf(decf(u.w), sc.w, sh.w), 0.f);
    *(float4*)((float*)vie_u + idx) = o;
}

// ---------------- MFMA fused GRU: h = (1-z)*n + z*v_in, plus BN stats ----------------
template <bool W16>
__global__ __launch_bounds__(256, 2) void k_gru_mfma(
    const float* __restrict__ vie, const u16* __restrict__ vin,
    const u16* __restrict__ wihb, const float* __restrict__ wihf,
    const u16* __restrict__ whhb, const float* __restrict__ whhf,
    const float* __restrict__ bih, const float* __restrict__ bhh,
    u16* __restrict__ hout, double* __restrict__ stats_v)
{
    __shared__ u16 Ae[64][264];   // vie (bf16-staged)
    __shared__ u16 Av[64][264];   // vin
    __shared__ float csum[256], csq[256];
    int t = threadIdx.x;
    int row0 = blockIdx.x * 64;
    int rows = min(64, N - row0);
    int r = t >> 2, q = t & 3;
    if (r < rows) {
        const float* gp = vie + (size_t)(row0 + r) * H + q * 64;
        const u16* hp = vin + (size_t)(row0 + r) * H + q * 64;
#pragma unroll
        for (int i = 0; i < 16; ++i) {
            float4 v = *(const float4*)(gp + i * 4);
            *(ushort4*)&Ae[r][q * 64 + i * 4] = make_ushort4(f2bf(v.x), f2bf(v.y), f2bf(v.z), f2bf(v.w));
            *(ushort4*)&Av[r][q * 64 + i * 4] = *(const ushort4*)(hp + i * 4);
        }
    } else {
#pragma unroll
        for (int i = 0; i < 16; ++i) {
            *(ushort4*)&Ae[r][q * 64 + i * 4] = make_ushort4(0, 0, 0, 0);
            *(ushort4*)&Av[r][q * 64 + i * 4] = make_ushort4(0, 0, 0, 0);
        }
    }
    __syncthreads();
    int w = t >> 6, l = t & 63, lane16 = l & 15, quad = l >> 4;

    for (int g = 0; g < 4; ++g) {
        int j = g * 64 + w * 16 + lane16;
        f32x4 aR[4], aZ[4], aIG[4], aHG[4];
#pragma unroll
        for (int mt = 0; mt < 4; ++mt) {
            aR[mt] = (f32x4){0.f, 0.f, 0.f, 0.f};  aZ[mt] = (f32x4){0.f, 0.f, 0.f, 0.f};
            aIG[mt] = (f32x4){0.f, 0.f, 0.f, 0.f}; aHG[mt] = (f32x4){0.f, 0.f, 0.f, 0.f};
        }
        for (int k0 = 0; k0 < H; k0 += 32) {
            size_t kq = (size_t)k0 + quad * 8;
            bf16x8 ae[4], av[4];
#pragma unroll
            for (int mt = 0; mt < 4; ++mt) {
                ae[mt] = *(const bf16x8*)&Ae[mt * 16 + lane16][k0 + quad * 8];
                av[mt] = *(const bf16x8*)&Av[mt * 16 + lane16][k0 + quad * 8];
            }
            bf16x8 bri = ldb<W16>(wihb, wihf, (size_t)j * H + kq);
            bf16x8 bzi = ldb<W16>(wihb, wihf, (size_t)(H + j) * H + kq);
            bf16x8 bgi = ldb<W16>(wihb, wihf, (size_t)(2 * H + j) * H + kq);
            bf16x8 brh = ldb<W16>(whhb, whhf, (size_t)j * H + kq);
            bf16x8 bzh = ldb<W16>(whhb, whhf, (size_t)(H + j) * H + kq);
            bf16x8 bgh = ldb<W16>(whhb, whhf, (size_t)(2 * H + j) * H + kq);
#pragma unroll
            for (int mt = 0; mt < 4; ++mt) {
                aR[mt]  = __builtin_amdgcn_mfma_f32_16x16x32_bf16(ae[mt], bri, aR[mt], 0, 0, 0);
                aR[mt]  = __builtin_amdgcn_mfma_f32_16x16x32_bf16(av[mt], brh, aR[mt], 0, 0, 0);
                aZ[mt]  = __builtin_amdgcn_mfma_f32_16x16x32_bf16(ae[mt], bzi, aZ[mt], 0, 0, 0);
                aZ[mt]  = __builtin_amdgcn_mfma_f32_16x16x32_bf16(av[mt], bzh, aZ[mt], 0, 0, 0);
                aIG[mt] = __builtin_amdgcn_mfma_f32_16x16x32_bf16(ae[mt], bgi, aIG[mt], 0, 0, 0);
                aHG[mt] = __builtin_amdgcn_mfma_f32_16x16x32_bf16(av[mt], bgh, aHG[mt], 0, 0, 0);
            }
        }
        float br_ = bih[j] + bhh[j];
        float bz_ = bih[H + j] + bhh[H + j];
        float bgi_ = bih[2 * H + j];
        float bgh_ = bhh[2 * H + j];
        float s = 0.f, qq = 0.f;
#pragma unroll
        for (int mt = 0; mt < 4; ++mt)
#pragma unroll
            for (int reg = 0; reg < 4; ++reg) {
                int row = mt * 16 + quad * 4 + reg;
                float rr = sigmf(aR[mt][reg] + br_);
                float zz = sigmf(aZ[mt][reg] + bz_);
                float nn = tanhf_(aIG[mt][reg] + bgi_ + rr * (aHG[mt][reg] + bgh_));
                float vv = bf2f(Av[row][j]);
                float hv = (1.f - zz) * nn + zz * vv;
                if (row < rows) {
                    hout[(size_t)(row0 + row) * H + j] = f2bf(hv);
                    s += hv; qq += hv * hv;
                }
            }
        s  += __shfl_xor(s, 16, 64);  s  += __shfl_xor(s, 32, 64);
        qq += __shfl_xor(qq, 16, 64); qq += __shfl_xor(qq, 32, 64);
        if (quad == 0) { csum[j] = s; csq[j] = qq; }
    }
    __syncthreads();
    atomicAdd(&stats_v[t], (double)csum[t]);
    atomicAdd(&stats_v[256 + t], (double)csq[t]);
}

// ---------------- vertex update: v_in += relu(h*scale+shift) (bf16 rmw) ----------------
__global__ void k_vertex_update(u16* __restrict__ vin, const u16* __restrict__ h,
                                const float* __restrict__ scale, const float* __restrict__ shift) {
    size_t idx = ((size_t)blockIdx.x * 256 + threadIdx.x) * 4;
    int col = (int)(idx & (size_t)(H - 1));
    ushort4 hv = *(const ushort4*)(h + idx);
    float4 sc = *(const float4*)(scale + col);
    float4 sh = *(const float4*)(shift + col);
    ushort4 vv = *(const ushort4*)(vin + idx);
    float o0 = bf2f(vv.x) + fmaxf(fmaf(bf2f(hv.x), sc.x, sh.x), 0.f);
    float o1 = bf2f(vv.y) + fmaxf(fmaf(bf2f(hv.y), sc.y, sh.y), 0.f);
    float o2 = bf2f(vv.z) + fmaxf(fmaf(bf2f(hv.z), sc.z, sh.z), 0.f);
    float o3 = bf2f(vv.w) + fmaxf(fmaf(bf2f(hv.w), sc.w, sh.w), 0.f);
    *(ushort4*)(vin + idx) = make_ushort4(f2bf(o0), f2bf(o1), f2bf(o2), f2bf(o3));
}

// ---------------- final: out[orig_e(p)] = e_in2[p] . w_fo + b_fo ----------------
__global__ __launch_bounds__(256) void k_final(const u16* __restrict__ ein2,
                                               const int4* __restrict__ sd2,
                                               const float* __restrict__ w_fo, float* __restrict__ out) {
    int t = threadIdx.x;
    int lane = t & 63;
    int w = (blockIdx.x << 2) + (t >> 6);
    float4 wv = *(const float4*)(w_fo + lane * 4);
    float bfo = w_fo[H];
    int p0 = w * 64;
    for (int p = p0; p < p0 + 64; ++p) {
        ushort4 u = *(const ushort4*)(ein2 + (size_t)p * H + lane * 4);
        float s = bf2f(u.x) * wv.x + bf2f(u.y) * wv.y + bf2f(u.z) * wv.z + bf2f(u.w) * wv.w;
        for (int off = 32; off > 0; off >>= 1) s += __shfl_down(s, off, 64);
        if (lane == 0) out[sd2[p].z] = s + bfo;
    }
}

// ---------------- pipeline ----------------
template <bool W16>
static void run_all(void* const* d_in, void* d_out, void* d_ws, hipStream_t stream) {
    const float* x         = (const float*)d_in[0];
    const float* edge_attr = (const float*)d_in[1];
    const int*   ei        = (const int*)d_in[2];
    const int*   src = ei;
    const int*   dst = ei + E;
    const float* ew  = (const float*)d_in[3];
    const float* eb  = (const float*)d_in[4];
    const float* vw  = (const float*)d_in[5];
    const float* vb  = (const float*)d_in[6];
    const float* Le_w = (const float*)d_in[7];
    // d_in[8] = Le_b : cancels in BN
    const float* Lv_w = (const float*)d_in[9];
    // d_in[10] = Lv_b : cancels in BN
    const float* bne_g = (const float*)d_in[11];
    const float* bne_b = (const float*)d_in[12];
    const float* bnv_g = (const float*)d_in[13];
    const float* bnv_b = (const float*)d_in[14];
    const float* gwih  = (const float*)d_in[15];
    const float* gwhh  = (const float*)d_in[16];
    const float* gbih  = (const float*)d_in[17];
    const float* gbhh  = (const float*)d_in[18];
    const float* fin_w = (const float*)d_in[19];
    const float* fin_b = (const float*)d_in[20];
    const float* out_w = (const float*)d_in[21];
    const float* out_b = (const float*)d_in[22];
    float* out = (float*)d_out;

    const size_t nh = (size_t)N * H, eh = (size_t)E * H;
    char* base = (char*)d_ws;
    size_t off = 0;
    auto alloc = [&](size_t bytes) -> char* {
        char* p = base + off;
        off = (off + bytes + 255) & ~(size_t)255;
        return p;
    };
    float* w_fo = (float*)alloc((H + 1) * sizeof(float));
    u16* v_in = (u16*)alloc(nh * sizeof(u16));
    u16* vp   = (u16*)alloc(nh * sizeof(u16));          // aliased as hbuf after edge passes
    unsigned int* vie_u = (unsigned int*)alloc(nh * sizeof(unsigned int));
    u16* e_in = (u16*)alloc(eh * sizeof(u16));          // stored in dst-CSR order
    u16* wbf  = (u16*)alloc((size_t)NL * H * H * sizeof(u16));   // Le_w bf16 (always)
    double* stats_e = (double*)alloc((size_t)64 * 512 * sizeof(double));
    double* stats_v = (double*)alloc(512 * sizeof(double));
    float* scale_e = (float*)alloc(H * sizeof(float));
    float* shift_e = (float*)alloc(H * sizeof(float));
    float* scale_v = (float*)alloc(H * sizeof(float));
    float* shift_v = (float*)alloc(H * sizeof(float));
    int* curS = (int*)alloc((size_t)N * sizeof(int));
    int* curD = (int*)alloc((size_t)N * sizeof(int));
    int4* adjS = (int4*)alloc((size_t)E * sizeof(int4));
    int4* sd2  = (int4*)alloc((size_t)E * sizeof(int4));
    int*  pos  = (int*)alloc((size_t)E * sizeof(int));
    // optional bf16 weight copies (only consumed when W16)
    u16 *wbf_v = nullptr, *wbf_ih = nullptr, *wbf_hh = nullptr, *ew_b = nullptr, *vw_b = nullptr;
    if (W16) {
        wbf_v  = (u16*)alloc((size_t)NL * H * H * sizeof(u16));
        wbf_ih = (u16*)alloc((size_t)NL * 3 * H * H * sizeof(u16));
        wbf_hh = (u16*)alloc((size_t)NL * 3 * H * H * sizeof(u16));
        ew_b   = (u16*)alloc((size_t)H * FEAT * sizeof(u16));
        vw_b   = (u16*)alloc((size_t)H * FEAT * sizeof(u16));
    }
    u16* hbuf = vp;  // vp dead after edge passes; GRU writes here

    // fused final weights; bf16 weight conversions
    k_fuse_final<<<1, 256, 0, stream>>>(fin_w, fin_b, out_w, out_b, w_fo);
    k_cvt_w<<<(NL * H * H / 4 + 255) / 256, 256, 0, stream>>>(Le_w, wbf, NL * H * H / 4);
    if (W16) {
        k_cvt_w<<<(NL * H * H / 4 + 255) / 256, 256, 0, stream>>>(Lv_w, wbf_v, NL * H * H / 4);
        k_cvt_w<<<(NL * 3 * H * H / 4 + 255) / 256, 256, 0, stream>>>(gwih, wbf_ih, NL * 3 * H * H / 4);
        k_cvt_w<<<(NL * 3 * H * H / 4 + 255) / 256, 256, 0, stream>>>(gwhh, wbf_hh, NL * 3 * H * H / 4);
        k_cvt_w<<<(H * FEAT / 4 + 255) / 256, 256, 0, stream>>>(ew, ew_b, H * FEAT / 4);
        k_cvt_w<<<(H * FEAT / 4 + 255) / 256, 256, 0, stream>>>(vw, vw_b, H * FEAT / 4);
    }
    // CSR build + dst-order relabel
    k_zero_int<<<(N + 255) / 256, 256, 0, stream>>>(curS, N);
    k_zero_int<<<(N + 255) / 256, 256, 0, stream>>>(curD, N);
    k_hist2<<<E / 256, 256, 0, stream>>>(src, dst, curS, curD);
    k_scan<<<1, 256, 0, stream>>>(curS);
    k_scan<<<1, 256, 0, stream>>>(curD);
    k_fill_perm<<<E / 256, 256, 0, stream>>>(src, dst, curS, curD, adjS, sd2, pos);
    // input projections (MFMA, bf16 out); edge rows permuted into dst order
    const int ntile = (N + 63) / 64;
    k_proj_mfma<W16><<<ntile, 256, 0, stream>>>(x, vw_b, vw, vb, v_in, N, nullptr);
    k_proj_mfma<W16><<<E / 64, 256, 0, stream>>>(edge_attr, ew_b, ew, eb, e_in, E, pos);

    const int nstat = 64 * 512 + 512;
    for (int k = 0; k < NL; ++k) {
        k_zero_f64<<<(nstat + 255) / 256, 256, 0, stream>>>(stats_e, nstat);  // stats_v contiguous after
        k_fill_u32<<<(int)(nh / 4 / 256), 256, 0, stream>>>(vie_u, 0u);
        k_node_mfma<W16><<<ntile, 256, 0, stream>>>(v_in,
            W16 ? wbf_v + (size_t)k * H * H : nullptr, Lv_w + (size_t)k * H * H, vp);
        // dst pass: streaming (sequential e_in), stats + raw max
        k_edge_first<<<NB_E, 256, 0, stream>>>(e_in, wbf + (size_t)k * H * H, vp,
                                               sd2, curD, vie_u, stats_e);
        k_bn_final_e<<<1, 256, 0, stream>>>(stats_e, bne_g + k * H, bne_b + k * H, scale_e, shift_e);
        // src pass: gathered raw max + residual into e_in
        k_edge_second<<<NB_E, 256, 0, stream>>>(e_in, wbf + (size_t)k * H * H, vp,
                                                adjS, vie_u, scale_e, shift_e, e_in);
        k_vie_final<<<(int)(nh / 4 / 256), 256, 0, stream>>>(vie_u, scale_e, shift_e);
        k_gru_mfma<W16><<<ntile, 256, 0, stream>>>((const float*)vie_u, v_in,
            W16 ? wbf_ih + (size_t)k * 3 * H * H : nullptr, gwih + (size_t)k * 3 * H * H,
            W16 ? wbf_hh + (size_t)k * 3 * H * H : nullptr, gwhh + (size_t)k * 3 * H * H,
            gbih + (size_t)k * 3 * H, gbhh + (size_t)k * 3 * H, hbuf, stats_v);
        k_bn_final<<<1, 256, 0, stream>>>(stats_v, 0, bnv_g + k * H, bnv_b + k * H, (double)N, scale_v, shift_v);
        k_vertex_update<<<(int)(nh / 4 / 256), 256, 0, stream>>>(v_in, hbuf, scale_v, shift_v);
    }
    k_final<<<E / 256, 256, 0, stream>>>(e_in, sd2, w_fo, out);
}

// ---------------- host entry ----------------
extern "C" void kernel_launch(void* const* d_in, const int* in_sizes, int n_in,
                              void* d_out, int out_size, void* d_ws, size_t ws_size,
                              hipStream_t stream) {
    (void)in_sizes; (void)n_in; (void)out_size;
    const size_t nh = (size_t)N * H, eh = (size_t)E * H;
    auto rup = [](size_t x) { return (x + 255) & ~(size_t)255; };
    size_t need_base = rup((H + 1) * 4) + 2 * rup(nh * 2) + rup(nh * 4) + rup(eh * 2)
                     + rup((size_t)NL * H * H * 2) + rup((size_t)64 * 512 * 8) + rup(512 * 8)
                     + 4 * rup(H * 4) + 2 * rup((size_t)N * 4) + 2 * rup((size_t)E * 16)
                     + rup((size_t)E * 4);
    size_t need_w16 = rup((size_t)NL * H * H * 2)
                    + 2 * rup((size_t)NL * 3 * H * H * 2) + 2 * rup((size_t)H * FEAT * 2);
    if (ws_size == 0 || ws_size >= need_base + need_w16)
        run_all<true>(d_in, d_out, d_ws, stream);   // bf16 weight copies fit
    else
        run_all<false>(d_in, d_out, d_ws, stream);  // inline fp32->bf16 B-fragment converts
}

// Round 7
// 2443.557 us; speedup vs baseline: 1.3169x; 1.2401x over previous
//
#include <hip/hip_runtime.h>
#include <stdint.h>

// Problem constants
constexpr int N  = 20000;    // nodes
constexpr int E  = 320000;   // edges
constexpr int H  = 256;      // hidden
constexpr int FEAT = 64;     // FE == FV
constexpr int NL = 4;        // layers
constexpr int FL = 1024;
constexpr int NB_E = E / 64; // edge blocks per pass (64-row tiles)

typedef unsigned short u16;
typedef short bf16x8 __attribute__((ext_vector_type(8)));
typedef float f32x4 __attribute__((ext_vector_type(4)));

// ---------------- bf16 helpers (manual, RNE) ----------------
__device__ __forceinline__ float bf2f(u16 u) {
    union { uint32_t i; float f; } v; v.i = ((uint32_t)u) << 16; return v.f;
}
__device__ __forceinline__ u16 f2bf(float f) {
    union { uint32_t i; float f; } v; v.f = f;
    uint32_t r = v.i + 0x7FFFu + ((v.i >> 16) & 1u);
    return (u16)(r >> 16);
}
__device__ __forceinline__ float sigmf(float x) { return 1.f / (1.f + __expf(-x)); }
__device__ __forceinline__ float tanhf_(float x) { return 2.f / (1.f + __expf(-2.f * x)) - 1.f; }

// order-preserving float<->u32 encoding (for atomic max over signed floats)
__device__ __forceinline__ unsigned int encf(float x) {
    unsigned int u = __float_as_uint(x);
    return (u & 0x80000000u) ? ~u : (u | 0x80000000u);
}
__device__ __forceinline__ float decf(unsigned int k) {
    unsigned int u = (k & 0x80000000u) ? (k ^ 0x80000000u) : ~k;
    return __uint_as_float(u);
}
__device__ __forceinline__ bf16x8 addbf8(bf16x8 a, bf16x8 b) {
    bf16x8 o;
#pragma unroll
    for (int j = 0; j < 8; ++j)
        o[j] = (short)f2bf(bf2f((u16)(unsigned short)a[j]) + bf2f((u16)(unsigned short)b[j]));
    return o;
}

// B-fragment load: bf16 direct, or fp32 + inline convert (fallback when ws too small)
template <bool W16>
__device__ __forceinline__ bf16x8 ldb(const u16* wb, const float* wf, size_t off) {
    if constexpr (W16) {
        return *(const bf16x8*)(wb + off);
    } else {
        float4 b0 = *(const float4*)(wf + off);
        float4 b1 = *(const float4*)(wf + off + 4);
        bf16x8 r;
        r[0] = (short)f2bf(b0.x); r[1] = (short)f2bf(b0.y);
        r[2] = (short)f2bf(b0.z); r[3] = (short)f2bf(b0.w);
        r[4] = (short)f2bf(b1.x); r[5] = (short)f2bf(b1.y);
        r[6] = (short)f2bf(b1.z); r[7] = (short)f2bf(b1.w);
        return r;
    }
}

// ---------------- K0: fuse fin+out linear layers ----------------
__global__ void k_fuse_final(const float* __restrict__ fin_w, const float* __restrict__ fin_b,
                             const float* __restrict__ out_w, const float* __restrict__ out_b,
                             float* __restrict__ w_fo) {
    int h = threadIdx.x;
    float acc = 0.f;
    for (int f = 0; f < FL; ++f) acc = fmaf(out_w[f], fin_w[(size_t)f * H + h], acc);
    w_fo[h] = acc;
    if (h == 0) {
        float b = 0.f;
        for (int f = 0; f < FL; ++f) b = fmaf(out_w[f], fin_b[f], b);
        w_fo[H] = b + out_b[0];
    }
}

// ---------------- weight convert fp32 -> bf16 (row-major) ----------------
__global__ void k_cvt_w(const float* __restrict__ w, u16* __restrict__ o, int n4) {
    int i = blockIdx.x * 256 + threadIdx.x;
    if (i < n4) {
        float4 v = *(const float4*)(w + (size_t)i * 4);
        *(ushort4*)(o + (size_t)i * 4) = make_ushort4(f2bf(v.x), f2bf(v.y), f2bf(v.z), f2bf(v.w));
    }
}

// ---------------- weight convert fp32 -> bf16, MFMA-fragment order ----------------
// layout: [layer][g=row/16][ks=k/32][quad][lane16][8 elems] -> a wave's B-fragment
// load becomes 1KB contiguous instead of 64 scattered 16B requests.
__global__ void k_cvt_w_sw(const float* __restrict__ w, u16* __restrict__ o, int total) {
    int i = blockIdx.x * 256 + threadIdx.x;
    if (i >= total) return;
    int l16 = i & 15;
    int qd  = (i >> 4) & 3;
    int ks  = (i >> 6) & 7;      // H/32 = 8
    int g   = (i >> 9) & 15;     // H/16 = 16
    int ly  = i >> 13;
    int row = g * 16 + l16;
    int k   = ks * 32 + qd * 8;
    const float* src = w + ((size_t)ly * H + row) * H + k;
    u16* dst = o + (size_t)i * 8;
    *(ushort4*)dst       = make_ushort4(f2bf(src[0]), f2bf(src[1]), f2bf(src[2]), f2bf(src[3]));
    *(ushort4*)(dst + 4) = make_ushort4(f2bf(src[4]), f2bf(src[5]), f2bf(src[6]), f2bf(src[7]));
}

// ---------------- CSR build: dst-order edge relabel + src CSR over positions ----------------
__global__ void k_zero_int(int* __restrict__ p, int n) {
    int i = blockIdx.x * 256 + threadIdx.x;
    if (i < n) p[i] = 0;
}
__global__ void k_zero_f64(double* __restrict__ p, int n) {
    int i = blockIdx.x * 256 + threadIdx.x;
    if (i < n) p[i] = 0.0;
}
__global__ void k_hist2(const int* __restrict__ src, const int* __restrict__ dst,
                        int* __restrict__ curS, int* __restrict__ curD) {
    int e = blockIdx.x * 256 + threadIdx.x;
    if (e < E) { atomicAdd(&curS[src[e]], 1); atomicAdd(&curD[dst[e]], 1); }
}
__global__ void k_scan(int* __restrict__ cur) {
    __shared__ int cs[256];
    int t = threadIdx.x;
    constexpr int CH = (N + 255) / 256;
    int beg = t * CH, end = min(beg + CH, N);
    int s = 0;
    for (int i = beg; i < end; ++i) s += cur[i];
    cs[t] = s;
    __syncthreads();
    for (int off = 1; off < 256; off <<= 1) {
        int v = cs[t];
        int u = (t >= off) ? cs[t - off] : 0;
        __syncthreads();
        cs[t] = v + u;
        __syncthreads();
    }
    int run = (t > 0) ? cs[t - 1] : 0;
    for (int i = beg; i < end; ++i) { int d = cur[i]; cur[i] = run; run += d; }
}
// q = position of edge e in dst order. sd2[q]={src,dst,e}; pos[e]=q;
// adjS entries carry {position, src, dst, src-node}.
__global__ void k_fill_perm(const int* __restrict__ src, const int* __restrict__ dst,
                            int* __restrict__ curS, int* __restrict__ curD,
                            int4* __restrict__ adjS, int4* __restrict__ sd2, int* __restrict__ pos) {
    int e = blockIdx.x * 256 + threadIdx.x;
    if (e < E) {
        int s = src[e], d = dst[e];
        int q = atomicAdd(&curD[d], 1);
        sd2[q] = make_int4(s, d, e, 0);
        pos[e] = q;
        int p = atomicAdd(&curS[s], 1);
        adjS[p] = make_int4(q, s, d, s);
    }
    // after this kernel, curS[v]/curD[v] hold END offsets of node v
}
__global__ void k_fill_u32(unsigned int* __restrict__ p, unsigned int val) {
    size_t i = ((size_t)blockIdx.x * 256 + threadIdx.x) * 4;
    uint4 v = make_uint4(val, val, val, val);
    *(uint4*)(p + i) = v;
}

// ---------------- MFMA input projection: C[perm[m],256] = A[m,64] @ W^T + b, bf16 out ----------------
template <bool W16>
__global__ __launch_bounds__(256, 3) void k_proj_mfma(
    const float* __restrict__ A, const u16* __restrict__ wb, const float* __restrict__ wf,
    const float* __restrict__ bias, u16* __restrict__ C, int M, const int* __restrict__ perm)
{
    __shared__ u16 As[64][72];
    int t = threadIdx.x;
    int row0 = blockIdx.x * 64;
    int r = t >> 2, q = t & 3;
    if (row0 + r < M) {
        const float* gp = A + (size_t)(row0 + r) * FEAT + q * 16;
#pragma unroll
        for (int i = 0; i < 4; ++i) {
            float4 v = *(const float4*)(gp + i * 4);
            *(ushort4*)&As[r][q * 16 + i * 4] = make_ushort4(f2bf(v.x), f2bf(v.y), f2bf(v.z), f2bf(v.w));
        }
    } else {
#pragma unroll
        for (int i = 0; i < 4; ++i) *(ushort4*)&As[r][q * 16 + i * 4] = make_ushort4(0, 0, 0, 0);
    }
    __syncthreads();
    int w = t >> 6, l = t & 63, lane16 = l & 15, quad = l >> 4;
    f32x4 acc[4][4];
#pragma unroll
    for (int i = 0; i < 4; ++i)
#pragma unroll
        for (int j = 0; j < 4; ++j) acc[i][j] = (f32x4){0.f, 0.f, 0.f, 0.f};
#pragma unroll
    for (int k0 = 0; k0 < FEAT; k0 += 32) {
        bf16x8 a[4], b[4];
#pragma unroll
        for (int mt = 0; mt < 4; ++mt)
            a[mt] = *(const bf16x8*)&As[mt * 16 + lane16][k0 + quad * 8];
#pragma unroll
        for (int nt = 0; nt < 4; ++nt)
            b[nt] = ldb<W16>(wb, wf, (size_t)(w * 16 + nt * 64 + lane16) * FEAT + k0 + quad * 8);
#pragma unroll
        for (int mt = 0; mt < 4; ++mt)
#pragma unroll
            for (int nt = 0; nt < 4; ++nt)
                acc[mt][nt] = __builtin_amdgcn_mfma_f32_16x16x32_bf16(a[mt], b[nt], acc[mt][nt], 0, 0, 0);
    }
#pragma unroll
    for (int nt = 0; nt < 4; ++nt) {
        int col = w * 16 + nt * 64 + lane16;
        float bv = bias[col];
#pragma unroll
        for (int mt = 0; mt < 4; ++mt)
#pragma unroll
            for (int reg = 0; reg < 4; ++reg) {
                int row = mt * 16 + quad * 4 + reg;
                if (row0 + row < M) {
                    int pr = perm ? perm[row0 + row] : row0 + row;
                    C[(size_t)pr * H + col] = f2bf(acc[mt][nt][reg] + bv);
                }
            }
    }
}

// ---------------- MFMA node GEMM: vp = v_in @ Lv_w^T (Lv_b cancels in BN) ----------------
template <bool W16>
__global__ __launch_bounds__(256, 2) void k_node_mfma(
    const u16* __restrict__ A, const u16* __restrict__ wb, const float* __restrict__ wf,
    u16* __restrict__ C)
{
    __shared__ u16 As[64][264];
    int t = threadIdx.x;
    int row0 = blockIdx.x * 64;
    int rows = min(64, N - row0);
    int r = t >> 2, q = t & 3;
    if (r < rows) {
        const u16* gp = A + (size_t)(row0 + r) * H + q * 64;
#pragma unroll
        for (int i = 0; i < 16; ++i)
            *(ushort4*)&As[r][q * 64 + i * 4] = *(const ushort4*)(gp + i * 4);
    } else {
#pragma unroll
        for (int i = 0; i < 16; ++i) *(ushort4*)&As[r][q * 64 + i * 4] = make_ushort4(0, 0, 0, 0);
    }
    __syncthreads();
    int w = t >> 6, l = t & 63, lane16 = l & 15, quad = l >> 4;
    f32x4 acc[4][4];
#pragma unroll
    for (int i = 0; i < 4; ++i)
#pragma unroll
        for (int j = 0; j < 4; ++j) acc[i][j] = (f32x4){0.f, 0.f, 0.f, 0.f};
    for (int k0 = 0; k0 < H; k0 += 32) {
        bf16x8 a[4], b[4];
#pragma unroll
        for (int mt = 0; mt < 4; ++mt)
            a[mt] = *(const bf16x8*)&As[mt * 16 + lane16][k0 + quad * 8];
#pragma unroll
        for (int nt = 0; nt < 4; ++nt)
            b[nt] = ldb<W16>(wb, wf, (size_t)(w * 16 + nt * 64 + lane16) * H + k0 + quad * 8);
#pragma unroll
        for (int mt = 0; mt < 4; ++mt)
#pragma unroll
            for (int nt = 0; nt < 4; ++nt)
                acc[mt][nt] = __builtin_amdgcn_mfma_f32_16x16x32_bf16(a[mt], b[nt], acc[mt][nt], 0, 0, 0);
    }
#pragma unroll
    for (int nt = 0; nt < 4; ++nt) {
        int col = w * 16 + nt * 64 + lane16;
#pragma unroll
        for (int mt = 0; mt < 4; ++mt)
#pragma unroll
            for (int reg = 0; reg < 4; ++reg) {
                int row = mt * 16 + quad * 4 + reg;
                if (row < rows)
                    C[(size_t)(row0 + row) * H + col] = f2bf(acc[mt][nt][reg]);
            }
    }
}

// ---------------- edge pass A (dst order, streaming, 64 rows, 512 threads) ----------------
// raw[p][n] = (e_in2 @ Le_w^T)[p][n] + vp[src][n] + vp[dst][n]
// 8 waves: wave w covers cols [w*32, w*32+32). Weights read via fragment-order layout
// (1KB contiguous per wave-load). Walk: two independent 32-row segments.
__global__ __launch_bounds__(512, 4) void k_edge_first(
    const u16* __restrict__ ein2, const u16* __restrict__ wsw,
    const u16* __restrict__ vp, const int4* __restrict__ sd2,
    const int* __restrict__ endo,
    unsigned int* __restrict__ vie, double* __restrict__ stats_e)
{
    __shared__ u16 As[64][264];      // K-loop A tile; aliased as praw afterwards
    __shared__ u16 Us[64][264];      // vp[src]+vp[dst]
    __shared__ int s_node[64];
    __shared__ int s_int[64];
    u16 (*praw)[264] = As;

    int t = threadIdx.x;
    int p0 = blockIdx.x * 64;
    int r = t >> 3, q = t & 7;       // r: row 0..63, q: 32-col chunk 0..7
    {
        int4 en = sd2[p0 + r];       // {src, dst, e, 0}
        const u16* gp = ein2 + (size_t)(p0 + r) * H + q * 32;   // sequential
        const u16* vs = vp + (size_t)en.x * H + q * 32;
        const u16* vd = vp + (size_t)en.y * H + q * 32;
#pragma unroll
        for (int i = 0; i < 4; ++i)
            *(bf16x8*)&As[r][q * 32 + i * 8] = *(const bf16x8*)(gp + i * 8);
#pragma unroll
        for (int i = 0; i < 4; ++i) {
            bf16x8 a8 = *(const bf16x8*)(vs + i * 8);
            bf16x8 b8 = *(const bf16x8*)(vd + i * 8);
            *(bf16x8*)&Us[r][q * 32 + i * 8] = addbf8(a8, b8);
        }
    }
    if (t < 64) {
        int nd = sd2[p0 + t].y;
        s_node[t] = nd;
        int seg0 = p0 + (t & 32);    // 32-row segment start
        int st = (nd == 0) ? 0 : endo[nd - 1];
        int ee = endo[nd];
        s_int[t] = (st >= seg0) && (ee <= seg0 + 32);
    }
    __syncthreads();

    int w = t >> 6, l = t & 63, lane16 = l & 15, quad = l >> 4;
    f32x4 acc[4][2];
#pragma unroll
    for (int i = 0; i < 4; ++i)
#pragma unroll
        for (int j = 0; j < 2; ++j) acc[i][j] = (f32x4){0.f, 0.f, 0.f, 0.f};
    int woff = (quad * 16 + lane16) * 8;
    for (int ks = 0; ks < 8; ++ks) {
        int k0 = ks * 32;
        bf16x8 a[4], b[2];
#pragma unroll
        for (int mt = 0; mt < 4; ++mt)
            a[mt] = *(const bf16x8*)&As[mt * 16 + lane16][k0 + quad * 8];
#pragma unroll
        for (int nt = 0; nt < 2; ++nt)
            b[nt] = *(const bf16x8*)(wsw + (size_t)(w * 2 + nt) * 4096 + ks * 512 + woff);
#pragma unroll
        for (int mt = 0; mt < 4; ++mt)
#pragma unroll
            for (int nt = 0; nt < 2; ++nt)
                acc[mt][nt] = __builtin_amdgcn_mfma_f32_16x16x32_bf16(a[mt], b[nt], acc[mt][nt], 0, 0, 0);
    }
    __syncthreads();   // As reads complete -> region becomes praw

#pragma unroll
    for (int nt = 0; nt < 2; ++nt) {
        int col = w * 32 + nt * 16 + lane16;
        float s = 0.f, qq = 0.f;
#pragma unroll
        for (int mt = 0; mt < 4; ++mt)
#pragma unroll
            for (int reg = 0; reg < 4; ++reg) {
                int row = mt * 16 + quad * 4 + reg;
                float v = acc[mt][nt][reg] + bf2f(Us[row][col]);
                praw[row][col] = f2bf(v);
                s += v; qq += v * v;
            }
        s  += __shfl_xor(s, 16, 64);  s  += __shfl_xor(s, 32, 64);
        qq += __shfl_xor(qq, 16, 64); qq += __shfl_xor(qq, 32, 64);
        if (quad == 0) {
            int slice = blockIdx.x & 63;
            atomicAdd(&stats_e[(size_t)slice * 512 + col], (double)s);
            atomicAdd(&stats_e[(size_t)slice * 512 + 256 + col], (double)qq);
        }
    }
    __syncthreads();
    // segmented max walk: two 32-row segments; thread owns (seg, col)
    {
        int seg = t >> 8, col = t & 255;
        int base = seg * 32;
        int cur = s_node[base];
        float m = bf2f(praw[base][col]);
        for (int rr = 1; rr < 32; ++rr) {
            int nd = s_node[base + rr];
            float v = bf2f(praw[base + rr][col]);
            if (nd != cur) {
                if (s_int[base + rr - 1]) vie[(size_t)cur * H + col] = encf(m);  // sole writer
                else atomicMax(&vie[(size_t)cur * H + col], encf(m));
                cur = nd; m = v;
            } else m = fmaxf(m, v);
        }
        if (s_int[base + 31]) vie[(size_t)cur * H + col] = encf(m);
        else atomicMax(&vie[(size_t)cur * H + col], encf(m));
    }
}

// ---------------- edge pass B (src CSR, gathered, 64 rows, 512 threads) ----------------
__global__ __launch_bounds__(512, 4) void k_edge_second(
    const u16* __restrict__ ein2, const u16* __restrict__ wsw,
    const u16* __restrict__ vp, const int4* __restrict__ adj,
    unsigned int* __restrict__ vie,
    const float* __restrict__ scale, const float* __restrict__ shift,
    u16* __restrict__ ein_rw)
{
    __shared__ u16 As[64][264];
    __shared__ u16 Us[64][264];
    __shared__ int s_pos[64];
    __shared__ int s_node[64];
    u16 (*praw)[264] = As;

    int t = threadIdx.x;
    int p0 = blockIdx.x * 64;
    int r = t >> 3, q = t & 7;
    {
        int4 en = adj[p0 + r];       // {pos, src, dst, src-node}
        const u16* gp = ein2 + (size_t)en.x * H + q * 32;
        const u16* vs = vp + (size_t)en.y * H + q * 32;
        const u16* vd = vp + (size_t)en.z * H + q * 32;
#pragma unroll
        for (int i = 0; i < 4; ++i)
            *(bf16x8*)&As[r][q * 32 + i * 8] = *(const bf16x8*)(gp + i * 8);
#pragma unroll
        for (int i = 0; i < 4; ++i) {
            bf16x8 a8 = *(const bf16x8*)(vs + i * 8);
            bf16x8 b8 = *(const bf16x8*)(vd + i * 8);
            *(bf16x8*)&Us[r][q * 32 + i * 8] = addbf8(a8, b8);
        }
    }
    if (t < 64) {
        int4 en = adj[p0 + t];
        s_pos[t] = en.x; s_node[t] = en.w;
    }
    __syncthreads();

    int w = t >> 6, l = t & 63, lane16 = l & 15, quad = l >> 4;
    f32x4 acc[4][2];
#pragma unroll
    for (int i = 0; i < 4; ++i)
#pragma unroll
        for (int j = 0; j < 2; ++j) acc[i][j] = (f32x4){0.f, 0.f, 0.f, 0.f};
    int woff = (quad * 16 + lane16) * 8;
    for (int ks = 0; ks < 8; ++ks) {
        int k0 = ks * 32;
        bf16x8 a[4], b[2];
#pragma unroll
        for (int mt = 0; mt < 4; ++mt)
            a[mt] = *(const bf16x8*)&As[mt * 16 + lane16][k0 + quad * 8];
#pragma unroll
        for (int nt = 0; nt < 2; ++nt)
            b[nt] = *(const bf16x8*)(wsw + (size_t)(w * 2 + nt) * 4096 + ks * 512 + woff);
#pragma unroll
        for (int mt = 0; mt < 4; ++mt)
#pragma unroll
            for (int nt = 0; nt < 2; ++nt)
                acc[mt][nt] = __builtin_amdgcn_mfma_f32_16x16x32_bf16(a[mt], b[nt], acc[mt][nt], 0, 0, 0);
    }
    __syncthreads();

#pragma unroll
    for (int nt = 0; nt < 2; ++nt) {
        int col = w * 32 + nt * 16 + lane16;
#pragma unroll
        for (int mt = 0; mt < 4; ++mt)
#pragma unroll
            for (int reg = 0; reg < 4; ++reg) {
                int row = mt * 16 + quad * 4 + reg;
                praw[row][col] = f2bf(acc[mt][nt][reg] + bf2f(Us[row][col]));
            }
    }
    __syncthreads();
    // segmented max walk: two 32-row segments
    {
        int seg = t >> 8, col = t & 255;
        int base = seg * 32;
        int cur = s_node[base];
        float m = bf2f(praw[base][col]);
        for (int rr = 1; rr < 32; ++rr) {
            int nd = s_node[base + rr];
            float v = bf2f(praw[base + rr][col]);
            if (nd != cur) {
                atomicMax(&vie[(size_t)cur * H + col], encf(m));
                cur = nd; m = v;
            } else m = fmaxf(m, v);
        }
        atomicMax(&vie[(size_t)cur * H + col], encf(m));
    }
    {
        u16* gp = ein_rw + (size_t)s_pos[r] * H + q * 32;
        const float* scp = scale + q * 32;
        const float* shp = shift + q * 32;
#pragma unroll
        for (int i = 0; i < 8; ++i) {
            int c = q * 32 + i * 4;
            ushort2 pa = *(const ushort2*)&praw[r][c];
            ushort2 pb = *(const ushort2*)&praw[r][c + 2];
            float4 sc = *(const float4*)(scp + i * 4);
            float4 sh = *(const float4*)(shp + i * 4);
            ushort4 ev = *(const ushort4*)(gp + i * 4);
            float o0 = bf2f(ev.x) + fmaxf(fmaf(bf2f(pa.x), sc.x, sh.x), 0.f);
            float o1 = bf2f(ev.y) + fmaxf(fmaf(bf2f(pa.y), sc.y, sh.y), 0.f);
            float o2 = bf2f(ev.z) + fmaxf(fmaf(bf2f(pb.x), sc.z, sh.z), 0.f);
            float o3 = bf2f(ev.w) + fmaxf(fmaf(bf2f(pb.y), sc.w, sh.w), 0.f);
            *(ushort4*)(gp + i * 4) = make_ushort4(f2bf(o0), f2bf(o1), f2bf(o2), f2bf(o3));
        }
    }
}

// ---------------- BN finalize (edge: 64-slice reduce) ----------------
__global__ void k_bn_final_e(const double* __restrict__ stats_e,
                             const float* __restrict__ g, const float* __restrict__ b,
                             float* __restrict__ scale, float* __restrict__ shift) {
    int j = threadIdx.x;
    double m = 0.0, q = 0.0;
    for (int s = 0; s < 64; ++s) {
        m += stats_e[(size_t)s * 512 + j];
        q += stats_e[(size_t)s * 512 + 256 + j];
    }
    m /= (double)E;
    double var = q / (double)E - m * m;
    if (var < 0.0) var = 0.0;
    float inv = rsqrtf((float)var + 1e-5f);
    float sc = g[j] * inv;
    scale[j] = sc;
    shift[j] = b[j] - (float)m * sc;
}

// ---------------- BN finalize (node, single slice) ----------------
__global__ void k_bn_final(const double* __restrict__ stats, int base,
                           const float* __restrict__ g, const float* __restrict__ b,
                           double cnt, float* __restrict__ scale, float* __restrict__ shift) {
    int j = threadIdx.x;
    double m = stats[base + j] / cnt;
    double var = stats[base + 256 + j] / cnt - m * m;
    if (var < 0.0) var = 0.0;
    float inv = rsqrtf((float)var + 1e-5f);
    float sc = g[j] * inv;
    scale[j] = sc;
    shift[j] = b[j] - (float)m * sc;
}

// ---------------- vie finalize: decode raw max, affine+relu; untouched (isolated) -> 0 ----------------
__global__ void k_vie_final(unsigned int* __restrict__ vie_u,
                            const float* __restrict__ scale, const float* __restrict__ shift) {
    size_t idx = ((size_t)blockIdx.x * 256 + threadIdx.x) * 4;
    int col = (int)(idx & (size_t)(H - 1));
    uint4 u = *(const uint4*)(vie_u + idx);
    float4 sc = *(const float4*)(scale + col);
    float4 sh = *(const float4*)(shift + col);
    float4 o;
    o.x = (u.x == 0u) ? 0.f : fmaxf(fmaf(decf(u.x), sc.x, sh.x), 0.f);
    o.y = (u.y == 0u) ? 0.f : fmaxf(fmaf(decf(u.y), sc.y, sh.y), 0.f);
    o.z = (u.z == 0u) ? 0.f : fmaxf(fmaf(decf(u.z), sc.z, sh.z), 0.f);
    o.w = (u.w == 0u) ? 0.f : fmaxf(fmaf(decf(u.w), sc.w, sh.w), 0.f);
    *(float4*)((float*)vie_u + idx) = o;
}

// ---------------- MFMA fused GRU (32-row tiles): h = (1-z)*n + z*v_in, plus BN stats ----------------
template <bool W16>
__global__ __launch_bounds__(256, 3) void k_gru_mfma(
    const float* __restrict__ vie, const u16* __restrict__ vin,
    const u16* __restrict__ wihb, const float* __restrict__ wihf,
    const u16* __restrict__ whhb, const float* __restrict__ whhf,
    const float* __restrict__ bih, const float* __restrict__ bhh,
    u16* __restrict__ hout, double* __restrict__ stats_v)
{
    __shared__ u16 Ae[32][264];   // vie (bf16-staged)
    __shared__ u16 Av[32][264];   // vin
    __shared__ float csum[256], csq[256];
    int t = threadIdx.x;
    int row0 = blockIdx.x * 32;
    int rows = min(32, N - row0);
    int r = t >> 3, q = t & 7;
    if (r < rows) {
        const float* gp = vie + (size_t)(row0 + r) * H + q * 32;
        const u16* hp = vin + (size_t)(row0 + r) * H + q * 32;
#pragma unroll
        for (int i = 0; i < 8; ++i) {
            float4 v = *(const float4*)(gp + i * 4);
            *(ushort4*)&Ae[r][q * 32 + i * 4] = make_ushort4(f2bf(v.x), f2bf(v.y), f2bf(v.z), f2bf(v.w));
        }
#pragma unroll
        for (int i = 0; i < 4; ++i)
            *(bf16x8*)&Av[r][q * 32 + i * 8] = *(const bf16x8*)(hp + i * 8);
    } else {
#pragma unroll
        for (int i = 0; i < 8; ++i) {
            *(ushort4*)&Ae[r][q * 32 + i * 4] = make_ushort4(0, 0, 0, 0);
            *(ushort4*)&Av[r][q * 32 + i * 4] = make_ushort4(0, 0, 0, 0);
        }
    }
    __syncthreads();
    int w = t >> 6, l = t & 63, lane16 = l & 15, quad = l >> 4;

    for (int g = 0; g < 4; ++g) {
        int j = g * 64 + w * 16 + lane16;
        f32x4 aR[2], aZ[2], aIG[2], aHG[2];
#pragma unroll
        for (int mt = 0; mt < 2; ++mt) {
            aR[mt] = (f32x4){0.f, 0.f, 0.f, 0.f};  aZ[mt] = (f32x4){0.f, 0.f, 0.f, 0.f};
            aIG[mt] = (f32x4){0.f, 0.f, 0.f, 0.f}; aHG[mt] = (f32x4){0.f, 0.f, 0.f, 0.f};
        }
        for (int k0 = 0; k0 < H; k0 += 32) {
            size_t kq = (size_t)k0 + quad * 8;
            bf16x8 ae[2], av[2];
#pragma unroll
            for (int mt = 0; mt < 2; ++mt) {
                ae[mt] = *(const bf16x8*)&Ae[mt * 16 + lane16][k0 + quad * 8];
                av[mt] = *(const bf16x8*)&Av[mt * 16 + lane16][k0 + quad * 8];
            }
            bf16x8 bri = ldb<W16>(wihb, wihf, (size_t)j * H + kq);
            bf16x8 bzi = ldb<W16>(wihb, wihf, (size_t)(H + j) * H + kq);
            bf16x8 bgi = ldb<W16>(wihb, wihf, (size_t)(2 * H + j) * H + kq);
            bf16x8 brh = ldb<W16>(whhb, whhf, (size_t)j * H + kq);
            bf16x8 bzh = ldb<W16>(whhb, whhf, (size_t)(H + j) * H + kq);
            bf16x8 bgh = ldb<W16>(whhb, whhf, (size_t)(2 * H + j) * H + kq);
#pragma unroll
            for (int mt = 0; mt < 2; ++mt) {
                aR[mt]  = __builtin_amdgcn_mfma_f32_16x16x32_bf16(ae[mt], bri, aR[mt], 0, 0, 0);
                aR[mt]  = __builtin_amdgcn_mfma_f32_16x16x32_bf16(av[mt], brh, aR[mt], 0, 0, 0);
                aZ[mt]  = __builtin_amdgcn_mfma_f32_16x16x32_bf16(ae[mt], bzi, aZ[mt], 0, 0, 0);
                aZ[mt]  = __builtin_amdgcn_mfma_f32_16x16x32_bf16(av[mt], bzh, aZ[mt], 0, 0, 0);
                aIG[mt] = __builtin_amdgcn_mfma_f32_16x16x32_bf16(ae[mt], bgi, aIG[mt], 0, 0, 0);
                aHG[mt] = __builtin_amdgcn_mfma_f32_16x16x32_bf16(av[mt], bgh, aHG[mt], 0, 0, 0);
            }
        }
        float br_ = bih[j] + bhh[j];
        float bz_ = bih[H + j] + bhh[H + j];
        float bgi_ = bih[2 * H + j];
        float bgh_ = bhh[2 * H + j];
        float s = 0.f, qq = 0.f;
#pragma unroll
        for (int mt = 0; mt < 2; ++mt)
#pragma unroll
            for (int reg = 0; reg < 4; ++reg) {
                int row = mt * 16 + quad * 4 + reg;
                float rr = sigmf(aR[mt][reg] + br_);
                float zz = sigmf(aZ[mt][reg] + bz_);
                float nn = tanhf_(aIG[mt][reg] + bgi_ + rr * (aHG[mt][reg] + bgh_));
                float vv = bf2f(Av[row][j]);
                float hv = (1.f - zz) * nn + zz * vv;
                if (row < rows) {
                    hout[(size_t)(row0 + row) * H + j] = f2bf(hv);
                    s += hv; qq += hv * hv;
                }
            }
        s  += __shfl_xor(s, 16, 64);  s  += __shfl_xor(s, 32, 64);
        qq += __shfl_xor(qq, 16, 64); qq += __shfl_xor(qq, 32, 64);
        if (quad == 0) { csum[j] = s; csq[j] = qq; }
    }
    __syncthreads();
    atomicAdd(&stats_v[t], (double)csum[t]);
    atomicAdd(&stats_v[256 + t], (double)csq[t]);
}

// ---------------- vertex update: v_in += relu(h*scale+shift) (bf16 rmw) ----------------
__global__ void k_vertex_update(u16* __restrict__ vin, const u16* __restrict__ h,
                                const float* __restrict__ scale, const float* __restrict__ shift) {
    size_t idx = ((size_t)blockIdx.x * 256 + threadIdx.x) * 4;
    int col = (int)(idx & (size_t)(H - 1));
    ushort4 hv = *(const ushort4*)(h + idx);
    float4 sc = *(const float4*)(scale + col);
    float4 sh = *(const float4*)(shift + col);
    ushort4 vv = *(const ushort4*)(vin + idx);
    float o0 = bf2f(vv.x) + fmaxf(fmaf(bf2f(hv.x), sc.x, sh.x), 0.f);
    float o1 = bf2f(vv.y) + fmaxf(fmaf(bf2f(hv.y), sc.y, sh.y), 0.f);
    float o2 = bf2f(vv.z) + fmaxf(fmaf(bf2f(hv.z), sc.z, sh.z), 0.f);
    float o3 = bf2f(vv.w) + fmaxf(fmaf(bf2f(hv.w), sc.w, sh.w), 0.f);
    *(ushort4*)(vin + idx) = make_ushort4(f2bf(o0), f2bf(o1), f2bf(o2), f2bf(o3));
}

// ---------------- final: out[orig_e(p)] = e_in2[p] . w_fo + b_fo ----------------
__global__ __launch_bounds__(256) void k_final(const u16* __restrict__ ein2,
                                               const int4* __restrict__ sd2,
                                               const float* __restrict__ w_fo, float* __restrict__ out) {
    int t = threadIdx.x;
    int lane = t & 63;
    int w = (blockIdx.x << 2) + (t >> 6);
    float4 wv = *(const float4*)(w_fo + lane * 4);
    float bfo = w_fo[H];
    int p0 = w * 64;
    for (int p = p0; p < p0 + 64; ++p) {
        ushort4 u = *(const ushort4*)(ein2 + (size_t)p * H + lane * 4);
        float s = bf2f(u.x) * wv.x + bf2f(u.y) * wv.y + bf2f(u.z) * wv.z + bf2f(u.w) * wv.w;
        for (int off = 32; off > 0; off >>= 1) s += __shfl_down(s, off, 64);
        if (lane == 0) out[sd2[p].z] = s + bfo;
    }
}

// ---------------- pipeline ----------------
template <bool W16>
static void run_all(void* const* d_in, void* d_out, void* d_ws, hipStream_t stream) {
    const float* x         = (const float*)d_in[0];
    const float* edge_attr = (const float*)d_in[1];
    const int*   ei        = (const int*)d_in[2];
    const int*   src = ei;
    const int*   dst = ei + E;
    const float* ew  = (const float*)d_in[3];
    const float* eb  = (const float*)d_in[4];
    const float* vw  = (const float*)d_in[5];
    const float* vb  = (const float*)d_in[6];
    const float* Le_w = (const float*)d_in[7];
    // d_in[8] = Le_b : cancels in BN
    const float* Lv_w = (const float*)d_in[9];
    // d_in[10] = Lv_b : cancels in BN
    const float* bne_g = (const float*)d_in[11];
    const float* bne_b = (const float*)d_in[12];
    const float* bnv_g = (const float*)d_in[13];
    const float* bnv_b = (const float*)d_in[14];
    const float* gwih  = (const float*)d_in[15];
    const float* gwhh  = (const float*)d_in[16];
    const float* gbih  = (const float*)d_in[17];
    const float* gbhh  = (const float*)d_in[18];
    const float* fin_w = (const float*)d_in[19];
    const float* fin_b = (const float*)d_in[20];
    const float* out_w = (const float*)d_in[21];
    const float* out_b = (const float*)d_in[22];
    float* out = (float*)d_out;

    const size_t nh = (size_t)N * H, eh = (size_t)E * H;
    char* base = (char*)d_ws;
    size_t off = 0;
    auto alloc = [&](size_t bytes) -> char* {
        char* p = base + off;
        off = (off + bytes + 255) & ~(size_t)255;
        return p;
    };
    float* w_fo = (float*)alloc((H + 1) * sizeof(float));
    u16* v_in = (u16*)alloc(nh * sizeof(u16));
    u16* vp   = (u16*)alloc(nh * sizeof(u16));          // aliased as hbuf after edge passes
    unsigned int* vie_u = (unsigned int*)alloc(nh * sizeof(unsigned int));
    u16* e_in = (u16*)alloc(eh * sizeof(u16));          // stored in dst-CSR order
    u16* wbf  = (u16*)alloc((size_t)NL * H * H * sizeof(u16));   // Le_w bf16, fragment-order
    double* stats_e = (double*)alloc((size_t)64 * 512 * sizeof(double));
    double* stats_v = (double*)alloc(512 * sizeof(double));
    float* scale_e = (float*)alloc(H * sizeof(float));
    float* shift_e = (float*)alloc(H * sizeof(float));
    float* scale_v = (float*)alloc(H * sizeof(float));
    float* shift_v = (float*)alloc(H * sizeof(float));
    int* curS = (int*)alloc((size_t)N * sizeof(int));
    int* curD = (int*)alloc((size_t)N * sizeof(int));
    int4* adjS = (int4*)alloc((size_t)E * sizeof(int4));
    int4* sd2  = (int4*)alloc((size_t)E * sizeof(int4));
    int*  pos  = (int*)alloc((size_t)E * sizeof(int));
    // optional bf16 weight copies (only consumed when W16)
    u16 *wbf_v = nullptr, *wbf_ih = nullptr, *wbf_hh = nullptr, *ew_b = nullptr, *vw_b = nullptr;
    if (W16) {
        wbf_v  = (u16*)alloc((size_t)NL * H * H * sizeof(u16));
        wbf_ih = (u16*)alloc((size_t)NL * 3 * H * H * sizeof(u16));
        wbf_hh = (u16*)alloc((size_t)NL * 3 * H * H * sizeof(u16));
        ew_b   = (u16*)alloc((size_t)H * FEAT * sizeof(u16));
        vw_b   = (u16*)alloc((size_t)H * FEAT * sizeof(u16));
    }
    u16* hbuf = vp;  // vp dead after edge passes; GRU writes here

    // fused final weights; bf16 weight conversions
    k_fuse_final<<<1, 256, 0, stream>>>(fin_w, fin_b, out_w, out_b, w_fo);
    k_cvt_w_sw<<<(NL * H * H / 8 + 255) / 256, 256, 0, stream>>>(Le_w, wbf, NL * H * H / 8);
    if (W16) {
        k_cvt_w<<<(NL * H * H / 4 + 255) / 256, 256, 0, stream>>>(Lv_w, wbf_v, NL * H * H / 4);
        k_cvt_w<<<(NL * 3 * H * H / 4 + 255) / 256, 256, 0, stream>>>(gwih, wbf_ih, NL * 3 * H * H / 4);
        k_cvt_w<<<(NL * 3 * H * H / 4 + 255) / 256, 256, 0, stream>>>(gwhh, wbf_hh, NL * 3 * H * H / 4);
        k_cvt_w<<<(H * FEAT / 4 + 255) / 256, 256, 0, stream>>>(ew, ew_b, H * FEAT / 4);
        k_cvt_w<<<(H * FEAT / 4 + 255) / 256, 256, 0, stream>>>(vw, vw_b, H * FEAT / 4);
    }
    // CSR build + dst-order relabel
    k_zero_int<<<(N + 255) / 256, 256, 0, stream>>>(curS, N);
    k_zero_int<<<(N + 255) / 256, 256, 0, stream>>>(curD, N);
    k_hist2<<<E / 256, 256, 0, stream>>>(src, dst, curS, curD);
    k_scan<<<1, 256, 0, stream>>>(curS);
    k_scan<<<1, 256, 0, stream>>>(curD);
    k_fill_perm<<<E / 256, 256, 0, stream>>>(src, dst, curS, curD, adjS, sd2, pos);
    // input projections (MFMA, bf16 out); edge rows permuted into dst order
    const int ntile = (N + 63) / 64;
    k_proj_mfma<W16><<<ntile, 256, 0, stream>>>(x, vw_b, vw, vb, v_in, N, nullptr);
    k_proj_mfma<W16><<<E / 64, 256, 0, stream>>>(edge_attr, ew_b, ew, eb, e_in, E, pos);

    const int nstat = 64 * 512 + 512;
    const int gtile = (N + 31) / 32;
    for (int k = 0; k < NL; ++k) {
        k_zero_f64<<<(nstat + 255) / 256, 256, 0, stream>>>(stats_e, nstat);  // stats_v contiguous after
        k_fill_u32<<<(int)(nh / 4 / 256), 256, 0, stream>>>(vie_u, 0u);
        k_node_mfma<W16><<<ntile, 256, 0, stream>>>(v_in,
            W16 ? wbf_v + (size_t)k * H * H : nullptr, Lv_w + (size_t)k * H * H, vp);
        // dst pass: streaming (sequential e_in), stats + raw max
        k_edge_first<<<NB_E, 512, 0, stream>>>(e_in, wbf + (size_t)k * H * H, vp,
                                               sd2, curD, vie_u, stats_e);
        k_bn_final_e<<<1, 256, 0, stream>>>(stats_e, bne_g + k * H, bne_b + k * H, scale_e, shift_e);
        // src pass: gathered raw max + residual into e_in
        k_edge_second<<<NB_E, 512, 0, stream>>>(e_in, wbf + (size_t)k * H * H, vp,
                                                adjS, vie_u, scale_e, shift_e, e_in);
        k_vie_final<<<(int)(nh / 4 / 256), 256, 0, stream>>>(vie_u, scale_e, shift_e);
        k_gru_mfma<W16><<<gtile, 256, 0, stream>>>((const float*)vie_u, v_in,
            W16 ? wbf_ih + (size_t)k * 3 * H * H : nullptr, gwih + (size_t)k * 3 * H * H,
            W16 ? wbf_hh + (size_t)k * 3 * H * H : nullptr, gwhh + (size_t)k * 3 * H * H,
            gbih + (size_t)k * 3 * H, gbhh + (size_t)k * 3 * H, hbuf, stats_v);
        k_bn_final<<<1, 256, 0, stream>>>(stats_v, 0, bnv_g + k * H, bnv_b + k * H, (double)N, scale_v, shift_v);
        k_vertex_update<<<(int)(nh / 4 / 256), 256, 0, stream>>>(v_in, hbuf, scale_v, shift_v);
    }
    k_final<<<E / 256, 256, 0, stream>>>(e_in, sd2, w_fo, out);
}

// ---------------- host entry ----------------
extern "C" void kernel_launch(void* const* d_in, const int* in_sizes, int n_in,
                              void* d_out, int out_size, void* d_ws, size_t ws_size,
                              hipStream_t stream) {
    (void)in_sizes; (void)n_in; (void)out_size;
    const size_t nh = (size_t)N * H, eh = (size_t)E * H;
    auto rup = [](size_t x) { return (x + 255) & ~(size_t)255; };
    size_t need_base = rup((H + 1) * 4) + 2 * rup(nh * 2) + rup(nh * 4) + rup(eh * 2)
                     + rup((size_t)NL * H * H * 2) + rup((size_t)64 * 512 * 8) + rup(512 * 8)
                     + 4 * rup(H * 4) + 2 * rup((size_t)N * 4) + 2 * rup((size_t)E * 16)
                     + rup((size_t)E * 4);
    size_t need_w16 = rup((size_t)NL * H * H * 2)
                    + 2 * rup((size_t)NL * 3 * H * H * 2) + 2 * rup((size_t)H * FEAT * 2);
    if (ws_size == 0 || ws_size >= need_base + need_w16)
        run_all<true>(d_in, d_out, d_ws, stream);   // bf16 weight copies fit
    else
        run_all<false>(d_in, d_out, d_ws, stream);  // inline fp32->bf16 B-fragment converts
}